// Round 1
// baseline (258.517 us; speedup 1.0000x reference)
//
#include <hip/hip_runtime.h>
#include <math.h>

#define SEQ 512
#define HID 768
#define NBATCH 16
#define ROWS 8192
#define INV_SQRT_D 0.07216878364870323f

typedef short s8v __attribute__((ext_vector_type(8)));
typedef _Float16 h8v __attribute__((ext_vector_type(8)));
typedef float f4v __attribute__((ext_vector_type(4)));
typedef unsigned short u16;

// ---- fp16 helper (RNE) ----
__device__ __forceinline__ u16 f2h(float f) {
  _Float16 h = (_Float16)f;
  return __builtin_bit_cast(u16, h);
}

// ---------------------------------------------------------------------------
// fp16 GEMM core (R10): BK=64 via paired 32-wide sub-tiles, one barrier-pair
// per 64 K. LDS 32KB: sub0 {A@0,B@4096}, sub1 {A@8192,B@12288} (u16 idx).
// Swizzle (row,chunk)->row*32+((chunk+(row>>1))&3)*8: conflict-free b128 reads.
// ---------------------------------------------------------------------------
template <int KSTEPS>   // number of 32-wide steps; must be even
__device__ __forceinline__ void mm_core128(
    const u16* __restrict__ A, const int lda,
    const u16* __restrict__ B, const int ldb,
    u16* lds, f4v (&acc)[4][4])
{
  const int tid = threadIdx.x;
  const int w = tid >> 6, ln = tid & 63;
  const u16* src = (w >> 1) ? B : A;
  const int ld = (w >> 1) ? ldb : lda;
  const int half = w & 1;
  const int srow = ln >> 2;
  const int csw  = ((ln & 3) - (ln >> 3)) & 3;
  const int ml = ln & 15, quad = ln >> 4;
  const int fo2 = ((quad + ((ln >> 1) & 3)) & 3) * 8;
  const int wr = (w >> 1) * 64, wc = (w & 1) * 64;

  const u16* gp[4];
  int lpo[4];
#pragma unroll
  for (int t = 0; t < 4; ++t) {
    const int row = half * 64 + t * 16 + srow;
    gp[t]  = src + (size_t)row * ld + csw * 8;
    lpo[t] = (w >> 1) * 4096 + half * 2048 + t * 512 + ln * 8;
  }
  s8v c[8];
#pragma unroll
  for (int t = 0; t < 4; ++t) {
    c[t]     = *(const s8v*)gp[t];
    c[4 + t] = *(const s8v*)(gp[t] + 32);
  }

  for (int kp = 0; kp < KSTEPS / 2; ++kp) {
    __syncthreads();
#pragma unroll
    for (int t = 0; t < 4; ++t) {
      *(s8v*)&lds[lpo[t]]        = c[t];
      *(s8v*)&lds[8192 + lpo[t]] = c[4 + t];
    }
    __syncthreads();
    if (kp + 1 < KSTEPS / 2) {
      const int k0 = (kp + 1) * 64;
#pragma unroll
      for (int t = 0; t < 4; ++t) {
        c[t]     = *(const s8v*)(gp[t] + k0);
        c[4 + t] = *(const s8v*)(gp[t] + k0 + 32);
      }
    }
#pragma unroll
    for (int sub = 0; sub < 2; ++sub) {
      const int so = sub * 8192;
      h8v a[4], b[4];
#pragma unroll
      for (int i = 0; i < 4; ++i)
        a[i] = *(const h8v*)&lds[so + (wr + i * 16 + ml) * 32 + fo2];
#pragma unroll
      for (int j = 0; j < 4; ++j)
        b[j] = *(const h8v*)&lds[so + 4096 + (wc + j * 16 + ml) * 32 + fo2];
#pragma unroll
      for (int i = 0; i < 4; ++i)
#pragma unroll
        for (int j = 0; j < 4; ++j)
          acc[i][j] = __builtin_amdgcn_mfma_f32_16x16x32_f16(a[i], b[j], acc[i][j], 0, 0, 0);
    }
  }
}

// ---- prep: x -> fp16 ----
__global__ __launch_bounds__(256) void splitx(const float* __restrict__ x,
                                              u16* __restrict__ xh)
{
  const int i = blockIdx.x * 256 + threadIdx.x;
  const float4 v = ((const float4*)x)[i];
  ((ushort4*)xh)[i] = make_ushort4(f2h(v.x), f2h(v.y), f2h(v.z), f2h(v.w));
}

// ---- prep: transpose weights: WT[z][n][k] = W_z[k][n], fp16 ----
__global__ __launch_bounds__(256) void wsplit(
    const float* __restrict__ Wq, const float* __restrict__ Wk,
    const float* __restrict__ Wv, const float* __restrict__ Wo,
    u16* __restrict__ WTh)
{
  __shared__ float t[32][33];
  const int z = blockIdx.z;
  const float* W = (z == 0) ? Wq : (z == 1) ? Wk : (z == 2) ? Wv : Wo;
  const int n0 = blockIdx.x * 32, k0 = blockIdx.y * 32;
  const int tx = threadIdx.x & 31, ty = threadIdx.x >> 5;
#pragma unroll
  for (int i = 0; i < 4; ++i)
    t[ty + 8 * i][tx] = W[(size_t)(k0 + ty + 8 * i) * HID + n0 + tx];
  __syncthreads();
#pragma unroll
  for (int i = 0; i < 4; ++i) {
    const float v = t[tx][ty + 8 * i];
    const size_t idx = (size_t)z * HID * HID + (size_t)(n0 + ty + 8 * i) * HID + k0 + tx;
    WTh[idx] = f2h(v);
  }
}

// ---- QKV GEMM, XCD-swizzled 1D grid (1152 blocks), fp16 BK=64 core ----
__global__ __launch_bounds__(256, 3) void qkv_mm(
    const u16* __restrict__ xh, const u16* __restrict__ WTh,
    const float* __restrict__ bq, const float* __restrict__ bk, const float* __restrict__ bv,
    u16* __restrict__ qh, u16* __restrict__ kh, u16* __restrict__ vtmp16)
{
  __shared__ u16 lds[16384];
  const int id = blockIdx.x;
  const int xcd = id & 7;
  const int s = id >> 3;            // 0..143
  const int bx = s % 6;
  const int yl = (s / 6) & 7;
  const int z  = s / 48;
  const int bm = (yl * 8 + xcd) * 128;
  const int bn = bx * 128;
  const size_t wtoff = (size_t)z * HID * HID + (size_t)bn * HID;
  f4v acc[4][4];
#pragma unroll
  for (int i = 0; i < 4; ++i)
#pragma unroll
    for (int j = 0; j < 4; ++j) acc[i][j] = (f4v)0.f;
  mm_core128<24>(xh + (size_t)bm * HID, HID, WTh + wtoff, HID, lds, acc);
  const int tid = threadIdx.x, w = tid >> 6, ln = tid & 63;
  const int ml = ln & 15, quad = ln >> 4;
  const int wr = (w >> 1) * 64, wc = (w & 1) * 64;
  const float* bias = (z == 0) ? bq : (z == 1) ? bk : bv;
#pragma unroll
  for (int i = 0; i < 4; ++i)
#pragma unroll
    for (int j = 0; j < 4; ++j) {
      const int gcol = bn + wc + j * 16 + ml;
      const float bv_ = bias[gcol];
#pragma unroll
      for (int r = 0; r < 4; ++r) {
        const int grow = bm + wr + i * 16 + quad * 4 + r;
        const float v = acc[i][j][r] + bv_;
        const size_t idx = (size_t)grow * HID + gcol;
        if (z == 2)      vtmp16[idx] = f2h(v);
        else if (z == 0) qh[idx] = f2h(v);
        else             kh[idx] = f2h(v);
      }
    }
}

// ---- prep: transpose v (fp16 passthrough): vT[b][n][c] = vtmp16[b][c][n] ----
__global__ __launch_bounds__(256) void vtrans(const u16* __restrict__ vtmp16,
                                              u16* __restrict__ vTh)
{
  __shared__ u16 t[32][33];
  const int b = blockIdx.z, n0 = blockIdx.x * 32, c0 = blockIdx.y * 32;
  const int tx = threadIdx.x & 31, ty = threadIdx.x >> 5;
  const u16* src = vtmp16 + (size_t)b * SEQ * HID;
#pragma unroll
  for (int i = 0; i < 4; ++i)
    t[ty + 8 * i][tx] = src[(size_t)(c0 + ty + 8 * i) * HID + n0 + tx];
  __syncthreads();
#pragma unroll
  for (int i = 0; i < 4; ++i) {
    const size_t idx = (size_t)b * HID * SEQ + (size_t)(n0 + ty + 8 * i) * SEQ + c0 + tx;
    vTh[idx] = t[tx][ty + 8 * i];
  }
}

// ---------------------------------------------------------------------------
// FLASH-FUSED attention v2 (R12): barrier-minimal, staging-free.
//
// Per (b,h), K and V tiles are 192KB each and L2-resident (16 Q-blocks of the
// same head re-read them) -> MFMA B-fragments are loaded STRAIGHT from global
// (16B/lane, 4 quads share one 64B line, offsets fold into load immediates).
// This removes all phase-1/phase-3 LDS staging and their 44 barriers.
//
// Softmax is max-free (exact: softmax is shift-invariant; scores bounded by
// (||q|| ||k|| + rel)/sqrt(192) <= ~4.2 even at the Cauchy-Schwarz bound, so
// exp(s) <= e^4.2 ~ 67 -- safe in fp32 and fp16). P is stored UNNORMALIZED in
// LDS (fp16, row stride 520 = 512+8: breaks the row*1024B == bank-0 aliasing
// that caused the 1.57M bank-conflict cycles); 1/rowsum is applied in the
// epilogue. Exactly ONE __syncthreads (P + partial-sum visibility).
//
// Grid: 1024 1-D, XCD-bijective decode so all 16 Q-blocks of one (b,h) land
// on one XCD (K+V working set 8 heads x 392KB = 3.1MB < 4MB L2/XCD).
// LDS: P 32x520 u16 = 33.3KB (+red) -> 4 blocks/CU.
// ---------------------------------------------------------------------------
__global__ __launch_bounds__(256, 4) void attn_fused(
    const u16* __restrict__ qh, const u16* __restrict__ kh,
    const u16* __restrict__ vTh, u16* __restrict__ ch)
{
  __shared__ u16 lds[16640];          // P: 32 rows x 520
  __shared__ float red[4][32];        // per-wave row sums
  const int f = blockIdx.x;
  const int xcd = f & 7, s = f >> 3;  // s: 0..127
  const int z = xcd * 8 + (s >> 4);   // 0..63 ; 8 heads per XCD
  const int bm = (s & 15) * 32;
  const int b = z >> 2, hh = z & 3;
  const int tid = threadIdx.x, w = tid >> 6, ln = tid & 63;
  const int ml = ln & 15, quad = ln >> 4;
  const int fo2 = ((quad + ((ml >> 1) & 3)) & 3) * 8;

  const u16* qbase = qh + (size_t)(b * SEQ + bm) * HID + hh * 192;
  const u16* kbase = kh + (size_t)b * SEQ * HID + hh * 192;

  // ---- phase 1: QK^T straight from global (L2), no LDS, no barriers ----
  const u16* qp[2];
#pragma unroll
  for (int i = 0; i < 2; ++i)
    qp[i] = qbase + (size_t)(i * 16 + ml) * HID + quad * 8;
  const u16* kp[8];
#pragma unroll
  for (int j = 0; j < 8; ++j)
    kp[j] = kbase + (size_t)(w * 128 + j * 16 + ml) * HID + quad * 8;

  f4v acc[2][8];
#pragma unroll
  for (int i = 0; i < 2; ++i)
#pragma unroll
    for (int j = 0; j < 8; ++j) acc[i][j] = (f4v)0.f;

#pragma unroll
  for (int ks = 0; ks < 6; ++ks) {
    const int ko = ks * 32;
    h8v a[2];
#pragma unroll
    for (int i = 0; i < 2; ++i) a[i] = *(const h8v*)(qp[i] + ko);
#pragma unroll
    for (int jh = 0; jh < 2; ++jh) {      // j split in halves: caps live VGPRs
      h8v bf[4];
#pragma unroll
      for (int j = 0; j < 4; ++j) bf[j] = *(const h8v*)(kp[jh * 4 + j] + ko);
#pragma unroll
      for (int i = 0; i < 2; ++i)
#pragma unroll
        for (int j = 0; j < 4; ++j)
          acc[i][jh * 4 + j] =
              __builtin_amdgcn_mfma_f32_16x16x32_f16(a[i], bf[j], acc[i][jh * 4 + j], 0, 0, 0);
    }
  }

  // ---- transform + max-free exp + partial row sums ----
  float sm[2][4];
#pragma unroll
  for (int i = 0; i < 2; ++i)
#pragma unroll
    for (int r = 0; r < 4; ++r) sm[i][r] = 0.f;
#pragma unroll
  for (int i = 0; i < 2; ++i)
#pragma unroll
    for (int j = 0; j < 8; ++j) {
      const int scol = w * 128 + j * 16 + ml;
#pragma unroll
      for (int r = 0; r < 4; ++r) {
        const int srow = bm + i * 16 + quad * 4 + r;
        const float fd = fabsf((float)(srow - scol));
        const float rel = __expf(-0.1f * fminf(fd, 5.0f));
        const float p = __expf((acc[i][j][r] + rel) * INV_SQRT_D - 0.1f * fd);
        acc[i][j][r] = p;
        sm[i][r] += p;
      }
    }
#pragma unroll
  for (int i = 0; i < 2; ++i)
#pragma unroll
    for (int r = 0; r < 4; ++r) {
      float t = sm[i][r];
#pragma unroll
      for (int o = 1; o < 16; o <<= 1) t += __shfl_xor(t, o, 64);
      sm[i][r] = t;
    }
  if (ml == 0) {
#pragma unroll
    for (int i = 0; i < 2; ++i)
#pragma unroll
      for (int r = 0; r < 4; ++r) red[w][i * 16 + quad * 4 + r] = sm[i][r];
  }

  // ---- write P (unnormalized) fp16, swizzled, stride 520 ----
#pragma unroll
  for (int i = 0; i < 2; ++i)
#pragma unroll
    for (int r = 0; r < 4; ++r) {
      const int row = i * 16 + quad * 4 + r;        // local 0..31
      const int rsw = (row >> 1) & 3;
      const int rbase = row * 520;
#pragma unroll
      for (int j = 0; j < 8; ++j) {
        const int col = w * 128 + j * 16 + ml;
        const int addr = rbase + (col & ~31) + ((((col >> 3) & 3) + rsw) & 3) * 8 + (col & 7);
        lds[addr] = f2h(acc[i][j][r]);
      }
    }
  __syncthreads();   // the ONLY barrier: P + red visible to all waves

  float isum[2][4];
#pragma unroll
  for (int i = 0; i < 2; ++i)
#pragma unroll
    for (int r = 0; r < 4; ++r) {
      const int R = i * 16 + quad * 4 + r;
      isum[i][r] = 1.0f / (red[0][R] + red[1][R] + red[2][R] + red[3][R]);
    }

  // ---- phase 2: PV; A from LDS-P, B straight from global vT, no barriers ----
  const u16* vbase = vTh + (size_t)b * HID * SEQ + (size_t)(hh * 192) * SEQ;
  const u16* vp[3];
#pragma unroll
  for (int j = 0; j < 3; ++j)
    vp[j] = vbase + (size_t)(w * 48 + j * 16 + ml) * SEQ + quad * 8;

  f4v acc2[2][3];
#pragma unroll
  for (int i = 0; i < 2; ++i)
#pragma unroll
    for (int j = 0; j < 3; ++j) acc2[i][j] = (f4v)0.f;

#pragma unroll
  for (int ks = 0; ks < 16; ++ks) {
    h8v a2[2];
#pragma unroll
    for (int i = 0; i < 2; ++i)
      a2[i] = *(const h8v*)&lds[(i * 16 + ml) * 520 + ks * 32 + fo2];
    h8v b2[3];
#pragma unroll
    for (int j = 0; j < 3; ++j) b2[j] = *(const h8v*)(vp[j] + ks * 32);
#pragma unroll
    for (int i = 0; i < 2; ++i)
#pragma unroll
      for (int j = 0; j < 3; ++j)
        acc2[i][j] = __builtin_amdgcn_mfma_f32_16x16x32_f16(a2[i], b2[j], acc2[i][j], 0, 0, 0);
  }

  // ---- ctx out (normalize by 1/rowsum here) ----
#pragma unroll
  for (int i = 0; i < 2; ++i)
#pragma unroll
    for (int j = 0; j < 3; ++j) {
      const int gcol = hh * 192 + w * 48 + j * 16 + ml;
#pragma unroll
      for (int r = 0; r < 4; ++r) {
        const int m = bm + i * 16 + quad * 4 + r;
        ch[(size_t)(b * SEQ + m) * HID + gcol] = f2h(acc2[i][j][r] * isum[i][r]);
      }
    }
}

// ---- projection GEMM + bias + residual -> h fp32 (XCD-swizzled, fp16) ----
__global__ __launch_bounds__(256, 3) void proj_mm(
    const u16* __restrict__ ch, const u16* __restrict__ WTh,
    const float* __restrict__ bo, const float* __restrict__ x, float* __restrict__ h)
{
  __shared__ u16 lds[16384];
  const int id = blockIdx.x;
  const int xcd = id & 7;
  const int s = id >> 3;            // 0..47
  const int bx = s % 6;
  const int yl = s / 6;             // 0..7
  const int bm = (yl * 8 + xcd) * 128;
  const int bn = bx * 128;
  const size_t wtoff = (size_t)3 * HID * HID + (size_t)bn * HID;
  f4v acc[4][4];
#pragma unroll
  for (int i = 0; i < 4; ++i)
#pragma unroll
    for (int j = 0; j < 4; ++j) acc[i][j] = (f4v)0.f;
  mm_core128<24>(ch + (size_t)bm * HID, HID, WTh + wtoff, HID, lds, acc);
  const int tid = threadIdx.x, w = tid >> 6, ln = tid & 63;
  const int ml = ln & 15, quad = ln >> 4;
  const int wr = (w >> 1) * 64, wc = (w & 1) * 64;
#pragma unroll
  for (int i = 0; i < 4; ++i)
#pragma unroll
    for (int j = 0; j < 4; ++j) {
      const int gcol = bn + wc + j * 16 + ml;
      const float bv_ = bo[gcol];
#pragma unroll
      for (int r = 0; r < 4; ++r) {
        const int grow = bm + wr + i * 16 + quad * 4 + r;
        const size_t idx = (size_t)grow * HID + gcol;
        h[idx] = acc[i][j][r] + bv_ + x[idx];
      }
    }
}

// ---- LayerNorm + 9-label classifier ----
__global__ __launch_bounds__(256) void ln_logits_kernel(
    const float* __restrict__ h, const float* __restrict__ g,
    const float* __restrict__ bta, const float* __restrict__ Ws,
    const float* __restrict__ bsv, float* __restrict__ span)
{
  const int row = blockIdx.x;
  const int tid = threadIdx.x;
  const float* hr = h + (size_t)row * HID;
  const float x0 = hr[tid], x1 = hr[tid + 256], x2 = hr[tid + 512];
  float s = x0 + x1 + x2;
  float sq = x0 * x0 + x1 * x1 + x2 * x2;
#pragma unroll
  for (int o = 32; o > 0; o >>= 1) { s += __shfl_down(s, o, 64); sq += __shfl_down(sq, o, 64); }
  __shared__ float red[8];
  __shared__ float smu, srs;
  const int wid = tid >> 6, lid = tid & 63;
  if (lid == 0) { red[wid] = s; red[4 + wid] = sq; }
  __syncthreads();
  if (tid == 0) {
    const float ts = red[0] + red[1] + red[2] + red[3];
    const float tq = red[4] + red[5] + red[6] + red[7];
    const float mu = ts / 768.0f;
    const float var = tq / 768.0f - mu * mu;
    smu = mu; srs = rsqrtf(var + 1e-5f);
  }
  __syncthreads();
  const float mu = smu, rs = srs;
  const float n0 = (x0 - mu) * rs * g[tid] + bta[tid];
  const float n1 = (x1 - mu) * rs * g[tid + 256] + bta[tid + 256];
  const float n2 = (x2 - mu) * rs * g[tid + 512] + bta[tid + 512];
  float pl[9];
#pragma unroll
  for (int l = 0; l < 9; ++l)
    pl[l] = n0 * Ws[(size_t)tid * 9 + l]
          + n1 * Ws[(size_t)(tid + 256) * 9 + l]
          + n2 * Ws[(size_t)(tid + 512) * 9 + l];
#pragma unroll
  for (int l = 0; l < 9; ++l)
#pragma unroll
    for (int o = 32; o > 0; o >>= 1) pl[l] += __shfl_down(pl[l], o, 64);
  __shared__ float lred[4][9];
  if (lid == 0) {
#pragma unroll
    for (int l = 0; l < 9; ++l) lred[wid][l] = pl[l];
  }
  __syncthreads();
  if (tid < 9) {
    span[(size_t)row * 9 + tid] =
        lred[0][tid] + lred[1][tid] + lred[2][tid] + lred[3][tid] + bsv[tid];
  }
}

// ---- entity-bias bump ----
__global__ __launch_bounds__(256) void bump_kernel(
    const float* __restrict__ span, const float* __restrict__ eb, float* __restrict__ out)
{
  const int idx = blockIdx.x * 256 + threadIdx.x;
  if (idx >= ROWS) return;
  const int j = idx & (SEQ - 1);
  const float* sl = span + (size_t)idx * 9;
  float v[9];
#pragma unroll
  for (int l = 0; l < 9; ++l) v[l] = sl[l];
  if (j >= 1) {
    const float* sp = sl - 9;
    float m = sp[0]; int am = 0;
#pragma unroll
    for (int l = 1; l < 9; ++l) { const float t = sp[l]; if (t > m) { m = t; am = l; } }
    if (am == 1) v[2] += 2.0f * eb[2];
  }
#pragma unroll
  for (int l = 0; l < 9; ++l) out[(size_t)idx * 9 + l] = v[l];
}

extern "C" void kernel_launch(void* const* d_in, const int* in_sizes, int n_in,
                              void* d_out, int out_size, void* d_ws, size_t ws_size,
                              hipStream_t stream)
{
  (void)in_sizes; (void)n_in; (void)out_size; (void)ws_size;
  const float* x   = (const float*)d_in[0];
  const float* Wq  = (const float*)d_in[1];
  const float* bq  = (const float*)d_in[2];
  const float* Wk  = (const float*)d_in[3];
  const float* bk  = (const float*)d_in[4];
  const float* Wv  = (const float*)d_in[5];
  const float* bv  = (const float*)d_in[6];
  const float* Wo  = (const float*)d_in[7];
  const float* bo  = (const float*)d_in[8];
  const float* lng = (const float*)d_in[9];
  const float* lnb = (const float*)d_in[10];
  const float* Ws  = (const float*)d_in[11];
  const float* bs  = (const float*)d_in[12];
  const float* eb  = (const float*)d_in[13];
  float* out = (float*)d_out;

  char* ws = (char*)d_ws;
  u16* xh  = (u16*)(ws + 0);                       // fp16 x (12.6MB)
  u16* vTh = xh;                                   // reuse after qkv
  u16* WTh = (u16*)(ws + 25165824);                // fp16 WT (4 matrices)
  u16* qh  = (u16*)(ws + 34603008);
  u16* kh  = (u16*)(ws + 59768832);
  u16* vtmp16 = (u16*)(ws + 84934656);             // fp16 v (12.6MB)
  float* hb = (float*)(ws + 84934656);             // fp32 h (25MB, after vtrans)
  float* spanb = (float*)(ws + 152043520);
  u16* ctxh = qh;                                  // q dead after attn

  splitx<<<dim3(1572864 / 256), 256, 0, stream>>>(x, xh);
  wsplit<<<dim3(24, 24, 4), 256, 0, stream>>>(Wq, Wk, Wv, Wo, WTh);
  qkv_mm<<<dim3(1152), 256, 0, stream>>>(xh, WTh, bq, bk, bv, qh, kh, vtmp16);
  vtrans<<<dim3(24, 16, 16), 256, 0, stream>>>(vtmp16, vTh);
  attn_fused<<<dim3(1024), 256, 0, stream>>>(qh, kh, vTh, ctxh);
  proj_mm<<<dim3(384), 256, 0, stream>>>(ctxh, WTh, bo, x, hb);
  ln_logits_kernel<<<dim3(ROWS), 256, 0, stream>>>(hb, lng, lnb, Ws, bs, spanb);
  bump_kernel<<<dim3(ROWS / 256), 256, 0, stream>>>(spanb, eb, out);
}

// Round 2
// 228.256 us; speedup vs baseline: 1.1326x; 1.1326x over previous
//
#include <hip/hip_runtime.h>
#include <math.h>

#define SEQ 512
#define HID 768
#define NBATCH 16
#define ROWS 8192
#define INV_SQRT_D 0.07216878364870323f

typedef short s8v __attribute__((ext_vector_type(8)));
typedef _Float16 h8v __attribute__((ext_vector_type(8)));
typedef float f4v __attribute__((ext_vector_type(4)));
typedef unsigned short u16;

// ---- fp16 helper (RNE) ----
__device__ __forceinline__ u16 f2h(float f) {
  _Float16 h = (_Float16)f;
  return __builtin_bit_cast(u16, h);
}

// ---------------------------------------------------------------------------
// fp16 GEMM core (R10): BK=64 via paired 32-wide sub-tiles, one barrier-pair
// per 64 K. LDS 32KB: sub0 {A@0,B@4096}, sub1 {A@8192,B@12288} (u16 idx).
// Swizzle (row,chunk)->row*32+((chunk+(row>>1))&3)*8: conflict-free b128 reads.
// ---------------------------------------------------------------------------
template <int KSTEPS>   // number of 32-wide steps; must be even
__device__ __forceinline__ void mm_core128(
    const u16* __restrict__ A, const int lda,
    const u16* __restrict__ B, const int ldb,
    u16* lds, f4v (&acc)[4][4])
{
  const int tid = threadIdx.x;
  const int w = tid >> 6, ln = tid & 63;
  const u16* src = (w >> 1) ? B : A;
  const int ld = (w >> 1) ? ldb : lda;
  const int half = w & 1;
  const int srow = ln >> 2;
  const int csw  = ((ln & 3) - (ln >> 3)) & 3;
  const int ml = ln & 15, quad = ln >> 4;
  const int fo2 = ((quad + ((ln >> 1) & 3)) & 3) * 8;
  const int wr = (w >> 1) * 64, wc = (w & 1) * 64;

  const u16* gp[4];
  int lpo[4];
#pragma unroll
  for (int t = 0; t < 4; ++t) {
    const int row = half * 64 + t * 16 + srow;
    gp[t]  = src + (size_t)row * ld + csw * 8;
    lpo[t] = (w >> 1) * 4096 + half * 2048 + t * 512 + ln * 8;
  }
  s8v c[8];
#pragma unroll
  for (int t = 0; t < 4; ++t) {
    c[t]     = *(const s8v*)gp[t];
    c[4 + t] = *(const s8v*)(gp[t] + 32);
  }

  for (int kp = 0; kp < KSTEPS / 2; ++kp) {
    __syncthreads();
#pragma unroll
    for (int t = 0; t < 4; ++t) {
      *(s8v*)&lds[lpo[t]]        = c[t];
      *(s8v*)&lds[8192 + lpo[t]] = c[4 + t];
    }
    __syncthreads();
    if (kp + 1 < KSTEPS / 2) {
      const int k0 = (kp + 1) * 64;
#pragma unroll
      for (int t = 0; t < 4; ++t) {
        c[t]     = *(const s8v*)(gp[t] + k0);
        c[4 + t] = *(const s8v*)(gp[t] + k0 + 32);
      }
    }
#pragma unroll
    for (int sub = 0; sub < 2; ++sub) {
      const int so = sub * 8192;
      h8v a[4], b[4];
#pragma unroll
      for (int i = 0; i < 4; ++i)
        a[i] = *(const h8v*)&lds[so + (wr + i * 16 + ml) * 32 + fo2];
#pragma unroll
      for (int j = 0; j < 4; ++j)
        b[j] = *(const h8v*)&lds[so + 4096 + (wc + j * 16 + ml) * 32 + fo2];
#pragma unroll
      for (int i = 0; i < 4; ++i)
#pragma unroll
        for (int j = 0; j < 4; ++j)
          acc[i][j] = __builtin_amdgcn_mfma_f32_16x16x32_f16(a[i], b[j], acc[i][j], 0, 0, 0);
    }
  }
}

// ---- prep: x -> fp16 ----
__global__ __launch_bounds__(256) void splitx(const float* __restrict__ x,
                                              u16* __restrict__ xh)
{
  const int i = blockIdx.x * 256 + threadIdx.x;
  const float4 v = ((const float4*)x)[i];
  ((ushort4*)xh)[i] = make_ushort4(f2h(v.x), f2h(v.y), f2h(v.z), f2h(v.w));
}

// ---- prep: transpose weights: WT[z][n][k] = W_z[k][n], fp16 ----
__global__ __launch_bounds__(256) void wsplit(
    const float* __restrict__ Wq, const float* __restrict__ Wk,
    const float* __restrict__ Wv, const float* __restrict__ Wo,
    u16* __restrict__ WTh)
{
  __shared__ float t[32][33];
  const int z = blockIdx.z;
  const float* W = (z == 0) ? Wq : (z == 1) ? Wk : (z == 2) ? Wv : Wo;
  const int n0 = blockIdx.x * 32, k0 = blockIdx.y * 32;
  const int tx = threadIdx.x & 31, ty = threadIdx.x >> 5;
#pragma unroll
  for (int i = 0; i < 4; ++i)
    t[ty + 8 * i][tx] = W[(size_t)(k0 + ty + 8 * i) * HID + n0 + tx];
  __syncthreads();
#pragma unroll
  for (int i = 0; i < 4; ++i) {
    const float v = t[tx][ty + 8 * i];
    const size_t idx = (size_t)z * HID * HID + (size_t)(n0 + ty + 8 * i) * HID + k0 + tx;
    WTh[idx] = f2h(v);
  }
}

// ---- QKV GEMM, XCD-swizzled 1D grid (1152 blocks), fp16 BK=64 core ----
__global__ __launch_bounds__(256, 3) void qkv_mm(
    const u16* __restrict__ xh, const u16* __restrict__ WTh,
    const float* __restrict__ bq, const float* __restrict__ bk, const float* __restrict__ bv,
    u16* __restrict__ qh, u16* __restrict__ kh, u16* __restrict__ vtmp16)
{
  __shared__ u16 lds[16384];
  const int id = blockIdx.x;
  const int xcd = id & 7;
  const int s = id >> 3;            // 0..143
  const int bx = s % 6;
  const int yl = (s / 6) & 7;
  const int z  = s / 48;
  const int bm = (yl * 8 + xcd) * 128;
  const int bn = bx * 128;
  const size_t wtoff = (size_t)z * HID * HID + (size_t)bn * HID;
  f4v acc[4][4];
#pragma unroll
  for (int i = 0; i < 4; ++i)
#pragma unroll
    for (int j = 0; j < 4; ++j) acc[i][j] = (f4v)0.f;
  mm_core128<24>(xh + (size_t)bm * HID, HID, WTh + wtoff, HID, lds, acc);
  const int tid = threadIdx.x, w = tid >> 6, ln = tid & 63;
  const int ml = ln & 15, quad = ln >> 4;
  const int wr = (w >> 1) * 64, wc = (w & 1) * 64;
  const float* bias = (z == 0) ? bq : (z == 1) ? bk : bv;
#pragma unroll
  for (int i = 0; i < 4; ++i)
#pragma unroll
    for (int j = 0; j < 4; ++j) {
      const int gcol = bn + wc + j * 16 + ml;
      const float bv_ = bias[gcol];
#pragma unroll
      for (int r = 0; r < 4; ++r) {
        const int grow = bm + wr + i * 16 + quad * 4 + r;
        const float v = acc[i][j][r] + bv_;
        const size_t idx = (size_t)grow * HID + gcol;
        if (z == 2)      vtmp16[idx] = f2h(v);
        else if (z == 0) qh[idx] = f2h(v);
        else             kh[idx] = f2h(v);
      }
    }
}

// ---- prep: transpose v (fp16 passthrough): vT[b][n][c] = vtmp16[b][c][n] ----
__global__ __launch_bounds__(256) void vtrans(const u16* __restrict__ vtmp16,
                                              u16* __restrict__ vTh)
{
  __shared__ u16 t[32][33];
  const int b = blockIdx.z, n0 = blockIdx.x * 32, c0 = blockIdx.y * 32;
  const int tx = threadIdx.x & 31, ty = threadIdx.x >> 5;
  const u16* src = vtmp16 + (size_t)b * SEQ * HID;
#pragma unroll
  for (int i = 0; i < 4; ++i)
    t[ty + 8 * i][tx] = src[(size_t)(c0 + ty + 8 * i) * HID + n0 + tx];
  __syncthreads();
#pragma unroll
  for (int i = 0; i < 4; ++i) {
    const size_t idx = (size_t)b * HID * SEQ + (size_t)(n0 + ty + 8 * i) * SEQ + c0 + tx;
    vTh[idx] = t[tx][ty + 8 * i];
  }
}

// ---------------------------------------------------------------------------
// FLASH attention v3 (R13): single-pass over 8 K-blocks of 64 rows.
// Per block: 32 Q-rows x one (b,h). Q is a shared A-operand -> lives in
// REGISTERS (12 h8v), never in LDS. Per K-block j: stage K_j[64][200] and
// vT_j[192][72] (pads: stride % 64 == 8 u16 -> every b128 frag read hits the
// 8-cycle LDS minimum, conflict-free), prefetch j+1 into regs (latency hides
// under ~700cy of MFMA+softmax), QK^T (12 MFMA) -> max-free exp via g-table
// (g(d) = c*exp(-.1*min(|d|,5)) - .1|d|; exact since scores bounded ~4.2,
// validated R12: absmax unchanged) -> P_j[32][72] fp16 -> PV (12 MFMA).
// 3 barriers/K-block + 1 final = 25 total (vs 44 in R10); one sum-reduce at
// the end, normalize in epilogue. setprio(1) brackets MFMA clusters (T5).
// Grid 1024 XCD-bijective: 8 heads/XCD -> K+V set 3MB < 4MB L2 (validated
// R12: FETCH 110->30MB). LDS 62.5KB -> 2 blocks/CU.
// ---------------------------------------------------------------------------
__global__ __launch_bounds__(256, 2) void attn_fused(
    const u16* __restrict__ qh, const u16* __restrict__ kh,
    const u16* __restrict__ vTh, u16* __restrict__ ch)
{
  __shared__ u16 lds[28928];      // KT[64][200]@0, VT[192][72]@12800, PT[32][72]@26624
  __shared__ float gtab[1024];
  __shared__ float red[4][32];
  const int f = blockIdx.x;
  const int xcd = f & 7, s = f >> 3;   // s: 0..127
  const int z = xcd * 8 + (s >> 4);    // (b,h) 0..63, 8 heads per XCD
  const int bm = (s & 15) * 32;
  const int b = z >> 2, hh = z & 3;
  const int tid = threadIdx.x, w = tid >> 6, ln = tid & 63;
  const int ml = ln & 15, quad = ln >> 4;

  // g-table: idx = (srow - scol) + 511
  for (int t = tid; t < 1023; t += 256) {
    const float fd = fabsf((float)(t - 511));
    gtab[t] = INV_SQRT_D * __expf(-0.1f * fminf(fd, 5.0f)) - 0.1f * fd;
  }

  const u16* qbase = qh + (size_t)(b * SEQ + bm) * HID + hh * 192;
  const u16* kbase = kh + (size_t)b * SEQ * HID + hh * 192;
  const u16* vbase = vTh + (size_t)b * HID * SEQ + (size_t)(hh * 192) * SEQ;

  // Q fragments in registers (A-operand, identical for all waves)
  h8v qf[2][6];
#pragma unroll
  for (int i = 0; i < 2; ++i)
#pragma unroll
    for (int ks = 0; ks < 6; ++ks)
      qf[i][ks] = *(const h8v*)(qbase + (size_t)(i * 16 + ml) * HID + ks * 32 + quad * 8);

  // staging decomposition: 1536 8-u16 chunks each for K_j and vT_j
  int koff[6], kldso[6], voff[6], vldso[6];
#pragma unroll
  for (int c = 0; c < 6; ++c) {
    const int cc = c * 256 + tid;
    const int krow = cc / 24, kcol = cc % 24;      // K_j: [64 rows][24 chunks]
    koff[c]  = krow * HID + kcol * 8;
    kldso[c] = krow * 200 + kcol * 8;
    const int vrow = cc >> 3, vcol = cc & 7;       // vT_j: [192 rows][8 chunks]
    voff[c]  = vrow * SEQ + vcol * 8;
    vldso[c] = 12800 + vrow * 72 + vcol * 8;
  }
  s8v kc[6], vc[6];
#pragma unroll
  for (int c = 0; c < 6; ++c) {
    kc[c] = *(const s8v*)(kbase + koff[c]);
    vc[c] = *(const s8v*)(vbase + voff[c]);
  }

  f4v acc2[2][3];
#pragma unroll
  for (int i = 0; i < 2; ++i)
#pragma unroll
    for (int jj = 0; jj < 3; ++jj) acc2[i][jj] = (f4v)0.f;
  float rsum[2][4];
#pragma unroll
  for (int i = 0; i < 2; ++i)
#pragma unroll
    for (int r = 0; r < 4; ++r) rsum[i][r] = 0.f;

  for (int j = 0; j < 8; ++j) {
    __syncthreads();                       // b1: prev-iter LDS reads done
#pragma unroll
    for (int c = 0; c < 6; ++c) {
      *(s8v*)&lds[kldso[c]] = kc[c];
      *(s8v*)&lds[vldso[c]] = vc[c];
    }
    __syncthreads();                       // b2: K_j/vT_j (+gtab, j==0) visible
    if (j < 7) {                           // prefetch next K-block into regs
      const int ko = (j + 1) * 64;
#pragma unroll
      for (int c = 0; c < 6; ++c) {
        kc[c] = *(const s8v*)(kbase + (size_t)ko * HID + koff[c]);
        vc[c] = *(const s8v*)(vbase + ko + voff[c]);
      }
    }
    // ---- QK^T: 12 MFMA ----
    f4v sacc[2];
    sacc[0] = (f4v)0.f; sacc[1] = (f4v)0.f;
    __builtin_amdgcn_s_setprio(1);
#pragma unroll
    for (int ks = 0; ks < 6; ++ks) {
      const h8v kf = *(const h8v*)&lds[(w * 16 + ml) * 200 + ks * 32 + quad * 8];
      sacc[0] = __builtin_amdgcn_mfma_f32_16x16x32_f16(qf[0][ks], kf, sacc[0], 0, 0, 0);
      sacc[1] = __builtin_amdgcn_mfma_f32_16x16x32_f16(qf[1][ks], kf, sacc[1], 0, 0, 0);
    }
    __builtin_amdgcn_s_setprio(0);
    // ---- transform + P write (max-free exp; 1 exp/elem via g-table) ----
    const int scolg = j * 64 + w * 16 + ml;
#pragma unroll
    for (int i = 0; i < 2; ++i)
#pragma unroll
      for (int r = 0; r < 4; ++r) {
        const int lrow = i * 16 + quad * 4 + r;
        const float g = gtab[bm + lrow - scolg + 511];
        const float p = __expf(fmaf(sacc[i][r], INV_SQRT_D, g));
        rsum[i][r] += p;
        lds[26624 + lrow * 72 + w * 16 + ml] = f2h(p);
      }
    __syncthreads();                       // b3: P_j visible
    // ---- PV: 12 MFMA ----
    __builtin_amdgcn_s_setprio(1);
#pragma unroll
    for (int ks = 0; ks < 2; ++ks) {
      h8v pf[2], vf[3];
#pragma unroll
      for (int i = 0; i < 2; ++i)
        pf[i] = *(const h8v*)&lds[26624 + (i * 16 + ml) * 72 + ks * 32 + quad * 8];
#pragma unroll
      for (int jj = 0; jj < 3; ++jj)
        vf[jj] = *(const h8v*)&lds[12800 + (w * 48 + jj * 16 + ml) * 72 + ks * 32 + quad * 8];
#pragma unroll
      for (int i = 0; i < 2; ++i)
#pragma unroll
        for (int jj = 0; jj < 3; ++jj)
          acc2[i][jj] = __builtin_amdgcn_mfma_f32_16x16x32_f16(pf[i], vf[jj], acc2[i][jj], 0, 0, 0);
    }
    __builtin_amdgcn_s_setprio(0);
  }

  // ---- final row-sum reduce (single barrier) ----
#pragma unroll
  for (int i = 0; i < 2; ++i)
#pragma unroll
    for (int r = 0; r < 4; ++r) {
      float t = rsum[i][r];
#pragma unroll
      for (int o = 1; o < 16; o <<= 1) t += __shfl_xor(t, o, 64);
      rsum[i][r] = t;
    }
  if (ml == 0) {
#pragma unroll
    for (int i = 0; i < 2; ++i)
#pragma unroll
      for (int r = 0; r < 4; ++r) red[w][i * 16 + quad * 4 + r] = rsum[i][r];
  }
  __syncthreads();

  // ---- ctx out (normalize here) ----
#pragma unroll
  for (int i = 0; i < 2; ++i)
#pragma unroll
    for (int r = 0; r < 4; ++r) {
      const int R = i * 16 + quad * 4 + r;
      const float is = 1.0f / (red[0][R] + red[1][R] + red[2][R] + red[3][R]);
      const int m = bm + R;
#pragma unroll
      for (int jj = 0; jj < 3; ++jj) {
        const int gcol = hh * 192 + w * 48 + jj * 16 + ml;
        ch[(size_t)(b * SEQ + m) * HID + gcol] = f2h(acc2[i][jj][r] * is);
      }
    }
}

// ---- projection GEMM + bias + residual -> h fp32 (XCD-swizzled, fp16) ----
__global__ __launch_bounds__(256, 3) void proj_mm(
    const u16* __restrict__ ch, const u16* __restrict__ WTh,
    const float* __restrict__ bo, const float* __restrict__ x, float* __restrict__ h)
{
  __shared__ u16 lds[16384];
  const int id = blockIdx.x;
  const int xcd = id & 7;
  const int s = id >> 3;            // 0..47
  const int bx = s % 6;
  const int yl = s / 6;             // 0..7
  const int bm = (yl * 8 + xcd) * 128;
  const int bn = bx * 128;
  const size_t wtoff = (size_t)3 * HID * HID + (size_t)bn * HID;
  f4v acc[4][4];
#pragma unroll
  for (int i = 0; i < 4; ++i)
#pragma unroll
    for (int j = 0; j < 4; ++j) acc[i][j] = (f4v)0.f;
  mm_core128<24>(ch + (size_t)bm * HID, HID, WTh + wtoff, HID, lds, acc);
  const int tid = threadIdx.x, w = tid >> 6, ln = tid & 63;
  const int ml = ln & 15, quad = ln >> 4;
  const int wr = (w >> 1) * 64, wc = (w & 1) * 64;
#pragma unroll
  for (int i = 0; i < 4; ++i)
#pragma unroll
    for (int j = 0; j < 4; ++j) {
      const int gcol = bn + wc + j * 16 + ml;
      const float bv_ = bo[gcol];
#pragma unroll
      for (int r = 0; r < 4; ++r) {
        const int grow = bm + wr + i * 16 + quad * 4 + r;
        const size_t idx = (size_t)grow * HID + gcol;
        h[idx] = acc[i][j][r] + bv_ + x[idx];
      }
    }
}

// ---- LayerNorm + 9-label classifier ----
__global__ __launch_bounds__(256) void ln_logits_kernel(
    const float* __restrict__ h, const float* __restrict__ g,
    const float* __restrict__ bta, const float* __restrict__ Ws,
    const float* __restrict__ bsv, float* __restrict__ span)
{
  const int row = blockIdx.x;
  const int tid = threadIdx.x;
  const float* hr = h + (size_t)row * HID;
  const float x0 = hr[tid], x1 = hr[tid + 256], x2 = hr[tid + 512];
  float s = x0 + x1 + x2;
  float sq = x0 * x0 + x1 * x1 + x2 * x2;
#pragma unroll
  for (int o = 32; o > 0; o >>= 1) { s += __shfl_down(s, o, 64); sq += __shfl_down(sq, o, 64); }
  __shared__ float red[8];
  __shared__ float smu, srs;
  const int wid = tid >> 6, lid = tid & 63;
  if (lid == 0) { red[wid] = s; red[4 + wid] = sq; }
  __syncthreads();
  if (tid == 0) {
    const float ts = red[0] + red[1] + red[2] + red[3];
    const float tq = red[4] + red[5] + red[6] + red[7];
    const float mu = ts / 768.0f;
    const float var = tq / 768.0f - mu * mu;
    smu = mu; srs = rsqrtf(var + 1e-5f);
  }
  __syncthreads();
  const float mu = smu, rs = srs;
  const float n0 = (x0 - mu) * rs * g[tid] + bta[tid];
  const float n1 = (x1 - mu) * rs * g[tid + 256] + bta[tid + 256];
  const float n2 = (x2 - mu) * rs * g[tid + 512] + bta[tid + 512];
  float pl[9];
#pragma unroll
  for (int l = 0; l < 9; ++l)
    pl[l] = n0 * Ws[(size_t)tid * 9 + l]
          + n1 * Ws[(size_t)(tid + 256) * 9 + l]
          + n2 * Ws[(size_t)(tid + 512) * 9 + l];
#pragma unroll
  for (int l = 0; l < 9; ++l)
#pragma unroll
    for (int o = 32; o > 0; o >>= 1) pl[l] += __shfl_down(pl[l], o, 64);
  __shared__ float lred[4][9];
  if (lid == 0) {
#pragma unroll
    for (int l = 0; l < 9; ++l) lred[wid][l] = pl[l];
  }
  __syncthreads();
  if (tid < 9) {
    span[(size_t)row * 9 + tid] =
        lred[0][tid] + lred[1][tid] + lred[2][tid] + lred[3][tid] + bsv[tid];
  }
}

// ---- entity-bias bump ----
__global__ __launch_bounds__(256) void bump_kernel(
    const float* __restrict__ span, const float* __restrict__ eb, float* __restrict__ out)
{
  const int idx = blockIdx.x * 256 + threadIdx.x;
  if (idx >= ROWS) return;
  const int j = idx & (SEQ - 1);
  const float* sl = span + (size_t)idx * 9;
  float v[9];
#pragma unroll
  for (int l = 0; l < 9; ++l) v[l] = sl[l];
  if (j >= 1) {
    const float* sp = sl - 9;
    float m = sp[0]; int am = 0;
#pragma unroll
    for (int l = 1; l < 9; ++l) { const float t = sp[l]; if (t > m) { m = t; am = l; } }
    if (am == 1) v[2] += 2.0f * eb[2];
  }
#pragma unroll
  for (int l = 0; l < 9; ++l) out[(size_t)idx * 9 + l] = v[l];
}

extern "C" void kernel_launch(void* const* d_in, const int* in_sizes, int n_in,
                              void* d_out, int out_size, void* d_ws, size_t ws_size,
                              hipStream_t stream)
{
  (void)in_sizes; (void)n_in; (void)out_size; (void)ws_size;
  const float* x   = (const float*)d_in[0];
  const float* Wq  = (const float*)d_in[1];
  const float* bq  = (const float*)d_in[2];
  const float* Wk  = (const float*)d_in[3];
  const float* bk  = (const float*)d_in[4];
  const float* Wv  = (const float*)d_in[5];
  const float* bv  = (const float*)d_in[6];
  const float* Wo  = (const float*)d_in[7];
  const float* bo  = (const float*)d_in[8];
  const float* lng = (const float*)d_in[9];
  const float* lnb = (const float*)d_in[10];
  const float* Ws  = (const float*)d_in[11];
  const float* bs  = (const float*)d_in[12];
  const float* eb  = (const float*)d_in[13];
  float* out = (float*)d_out;

  char* ws = (char*)d_ws;
  u16* xh  = (u16*)(ws + 0);                       // fp16 x (12.6MB)
  u16* vTh = xh;                                   // reuse after qkv
  u16* WTh = (u16*)(ws + 25165824);                // fp16 WT (4 matrices)
  u16* qh  = (u16*)(ws + 34603008);
  u16* kh  = (u16*)(ws + 59768832);
  u16* vtmp16 = (u16*)(ws + 84934656);             // fp16 v (12.6MB)
  float* hb = (float*)(ws + 84934656);             // fp32 h (25MB, after vtrans)
  float* spanb = (float*)(ws + 152043520);
  u16* ctxh = qh;                                  // q dead after attn

  splitx<<<dim3(1572864 / 256), 256, 0, stream>>>(x, xh);
  wsplit<<<dim3(24, 24, 4), 256, 0, stream>>>(Wq, Wk, Wv, Wo, WTh);
  qkv_mm<<<dim3(1152), 256, 0, stream>>>(xh, WTh, bq, bk, bv, qh, kh, vtmp16);
  vtrans<<<dim3(24, 16, 16), 256, 0, stream>>>(vtmp16, vTh);
  attn_fused<<<dim3(1024), 256, 0, stream>>>(qh, kh, vTh, ctxh);
  proj_mm<<<dim3(384), 256, 0, stream>>>(ctxh, WTh, bo, x, hb);
  ln_logits_kernel<<<dim3(ROWS), 256, 0, stream>>>(hb, lng, lnb, Ws, bs, spanb);
  bump_kernel<<<dim3(ROWS / 256), 256, 0, stream>>>(spanb, eb, out);
}

// Round 3
// 226.777 us; speedup vs baseline: 1.1400x; 1.0065x over previous
//
#include <hip/hip_runtime.h>
#include <math.h>

#define SEQ 512
#define HID 768
#define NBATCH 16
#define ROWS 8192
#define INV_SQRT_D 0.07216878364870323f

typedef short s8v __attribute__((ext_vector_type(8)));
typedef _Float16 h8v __attribute__((ext_vector_type(8)));
typedef float f4v __attribute__((ext_vector_type(4)));
typedef unsigned short u16;

// ---- fp16 helper (RNE) ----
__device__ __forceinline__ u16 f2h(float f) {
  _Float16 h = (_Float16)f;
  return __builtin_bit_cast(u16, h);
}

// ---- async global->LDS 16B copy (m97/m151: 1.35x over reg-staging) ----
// LDS dest must be wave-uniform base (HW adds lane*16); global src is per-lane.
__device__ __forceinline__ void llds16(const u16* g, u16* l) {
  __builtin_amdgcn_global_load_lds(
      (const __attribute__((address_space(1))) void*)g,
      (__attribute__((address_space(3))) void*)l, 16, 0, 0);
}

// ---------------------------------------------------------------------------
// fp16 GEMM core (R13): BK=64 via paired 32-wide sub-tiles, staged with
// global_load_lds (direct-to-LDS DMA). Source address carries the csw
// pre-swizzle (m173 pattern: pre-swizzled global + linear-in-lane LDS dest),
// so LDS state is byte-identical to the old reg-staged version; fragment
// reads keep the same fo2 swizzle (conflict-free b128).
// LDS 32KB: sub0 {A@0,B@4096}, sub1 {A@8192,B@12288} (u16 idx).
// Per K-64 step: barrier -> 8x global_load_lds(16B) -> barrier (drains
// vmcnt) -> 32 MFMA. Latency hidden by cross-block TLP (3 blocks/CU).
// ---------------------------------------------------------------------------
template <int KSTEPS>   // number of 32-wide steps; must be even
__device__ __forceinline__ void mm_core128(
    const u16* __restrict__ A, const int lda,
    const u16* __restrict__ B, const int ldb,
    u16* lds, f4v (&acc)[4][4])
{
  const int tid = threadIdx.x;
  const int w = tid >> 6, ln = tid & 63;
  const u16* src = (w >> 1) ? B : A;
  const int ld = (w >> 1) ? ldb : lda;
  const int half = w & 1;
  const int srow = ln >> 2;
  const int csw  = ((ln & 3) - (ln >> 3)) & 3;
  const int ml = ln & 15;
  const int fo2 = (((ln >> 4) + ((ln >> 1) & 3)) & 3) * 8;
  const int wr = (w >> 1) * 64, wc = (w & 1) * 64;

  const u16* gp[4];
  u16* lp[4];
#pragma unroll
  for (int t = 0; t < 4; ++t) {
    const int row = half * 64 + t * 16 + srow;
    gp[t] = src + (size_t)row * ld + csw * 8;
    lp[t] = lds + (w >> 1) * 4096 + half * 2048 + t * 512;   // wave-uniform
  }

  for (int kp = 0; kp < KSTEPS / 2; ++kp) {
    const int k0 = kp * 64;
    __syncthreads();                       // prev-iter LDS reads done
#pragma unroll
    for (int t = 0; t < 4; ++t) {
      llds16(gp[t] + k0,      lp[t]);
      llds16(gp[t] + k0 + 32, lp[t] + 8192);
    }
    __syncthreads();                       // vmcnt(0) drain + visibility
#pragma unroll
    for (int sub = 0; sub < 2; ++sub) {
      const int so = sub * 8192;
      h8v a[4], b[4];
#pragma unroll
      for (int i = 0; i < 4; ++i)
        a[i] = *(const h8v*)&lds[so + (wr + i * 16 + ml) * 32 + fo2];
#pragma unroll
      for (int j = 0; j < 4; ++j)
        b[j] = *(const h8v*)&lds[so + 4096 + (wc + j * 16 + ml) * 32 + fo2];
#pragma unroll
      for (int i = 0; i < 4; ++i)
#pragma unroll
        for (int j = 0; j < 4; ++j)
          acc[i][j] = __builtin_amdgcn_mfma_f32_16x16x32_f16(a[i], b[j], acc[i][j], 0, 0, 0);
    }
  }
}

// ---- prep: x -> fp16 ----
__global__ __launch_bounds__(256) void splitx(const float* __restrict__ x,
                                              u16* __restrict__ xh)
{
  const int i = blockIdx.x * 256 + threadIdx.x;
  const float4 v = ((const float4*)x)[i];
  ((ushort4*)xh)[i] = make_ushort4(f2h(v.x), f2h(v.y), f2h(v.z), f2h(v.w));
}

// ---- prep: transpose weights: WT[z][n][k] = W_z[k][n], fp16 ----
__global__ __launch_bounds__(256) void wsplit(
    const float* __restrict__ Wq, const float* __restrict__ Wk,
    const float* __restrict__ Wv, const float* __restrict__ Wo,
    u16* __restrict__ WTh)
{
  __shared__ float t[32][33];
  const int z = blockIdx.z;
  const float* W = (z == 0) ? Wq : (z == 1) ? Wk : (z == 2) ? Wv : Wo;
  const int n0 = blockIdx.x * 32, k0 = blockIdx.y * 32;
  const int tx = threadIdx.x & 31, ty = threadIdx.x >> 5;
#pragma unroll
  for (int i = 0; i < 4; ++i)
    t[ty + 8 * i][tx] = W[(size_t)(k0 + ty + 8 * i) * HID + n0 + tx];
  __syncthreads();
#pragma unroll
  for (int i = 0; i < 4; ++i) {
    const float v = t[tx][ty + 8 * i];
    const size_t idx = (size_t)z * HID * HID + (size_t)(n0 + ty + 8 * i) * HID + k0 + tx;
    WTh[idx] = f2h(v);
  }
}

// ---- QKV GEMM, XCD-swizzled 1D grid (1152 blocks), gll fp16 BK=64 core.
//      z==2 (v) epilogue writes vT[b][n][seq] directly (vtrans folded in). ----
__global__ __launch_bounds__(256, 3) void qkv_mm(
    const u16* __restrict__ xh, const u16* __restrict__ WTh,
    const float* __restrict__ bq, const float* __restrict__ bk, const float* __restrict__ bv,
    u16* __restrict__ qh, u16* __restrict__ kh, u16* __restrict__ vTh)
{
  __shared__ u16 lds[16384];
  const int id = blockIdx.x;
  const int xcd = id & 7;
  const int s = id >> 3;            // 0..143
  const int bx = s % 6;
  const int yl = (s / 6) & 7;
  const int z  = s / 48;
  const int bm = (yl * 8 + xcd) * 128;
  const int bn = bx * 128;
  const size_t wtoff = (size_t)z * HID * HID + (size_t)bn * HID;
  f4v acc[4][4];
#pragma unroll
  for (int i = 0; i < 4; ++i)
#pragma unroll
    for (int j = 0; j < 4; ++j) acc[i][j] = (f4v)0.f;
  mm_core128<24>(xh + (size_t)bm * HID, HID, WTh + wtoff, HID, lds, acc);
  const int tid = threadIdx.x, w = tid >> 6, ln = tid & 63;
  const int ml = ln & 15, quad = ln >> 4;
  const int wr = (w >> 1) * 64, wc = (w & 1) * 64;
  if (z == 2) {
    // v: write transposed vT[b][n][seq]; 4 consecutive seq per thread -> 8B store
    u16* vb = vTh + (size_t)(bm >> 9) * HID * SEQ;
    const int spbase = (bm & 511) + wr + quad * 4;
#pragma unroll
    for (int i = 0; i < 4; ++i)
#pragma unroll
      for (int j = 0; j < 4; ++j) {
        const int gcol = bn + wc + j * 16 + ml;
        const float bv_ = bv[gcol];
        const ushort4 pk = make_ushort4(
            f2h(acc[i][j][0] + bv_), f2h(acc[i][j][1] + bv_),
            f2h(acc[i][j][2] + bv_), f2h(acc[i][j][3] + bv_));
        *(ushort4*)&vb[(size_t)gcol * SEQ + spbase + i * 16] = pk;
      }
  } else {
    const float* bias = (z == 0) ? bq : bk;
    u16* dst = (z == 0) ? qh : kh;
#pragma unroll
    for (int i = 0; i < 4; ++i)
#pragma unroll
      for (int j = 0; j < 4; ++j) {
        const int gcol = bn + wc + j * 16 + ml;
        const float bv_ = bias[gcol];
#pragma unroll
        for (int r = 0; r < 4; ++r) {
          const int grow = bm + wr + i * 16 + quad * 4 + r;
          dst[(size_t)grow * HID + gcol] = f2h(acc[i][j][r] + bv_);
        }
      }
  }
}

// ---------------------------------------------------------------------------
// FLASH attention v3 (R13): single-pass over 8 K-blocks of 64 rows.
// Per block: 32 Q-rows x one (b,h). Q in registers; per K-block: stage
// K_j[64][200] + vT_j[192][72] (padded strides: conflict-free b128), reg-
// prefetch j+1 under MFMA+softmax; QK^T (12 MFMA) -> max-free exp via g-table
// (exact; validated R11/R12) -> P_j[32][72] fp16 -> PV (12 MFMA).
// 25 barriers total; one sum-reduce at end; setprio around MFMA (T5).
// Grid 1024 XCD-bijective: 8 heads/XCD -> K+V set 3MB < 4MB L2.
// ---------------------------------------------------------------------------
__global__ __launch_bounds__(256, 2) void attn_fused(
    const u16* __restrict__ qh, const u16* __restrict__ kh,
    const u16* __restrict__ vTh, u16* __restrict__ ch)
{
  __shared__ u16 lds[28928];      // KT[64][200]@0, VT[192][72]@12800, PT[32][72]@26624
  __shared__ float gtab[1024];
  __shared__ float red[4][32];
  const int f = blockIdx.x;
  const int xcd = f & 7, s = f >> 3;   // s: 0..127
  const int z = xcd * 8 + (s >> 4);    // (b,h) 0..63, 8 heads per XCD
  const int bm = (s & 15) * 32;
  const int b = z >> 2, hh = z & 3;
  const int tid = threadIdx.x, w = tid >> 6, ln = tid & 63;
  const int ml = ln & 15, quad = ln >> 4;

  // g-table: idx = (srow - scol) + 511
  for (int t = tid; t < 1023; t += 256) {
    const float fd = fabsf((float)(t - 511));
    gtab[t] = INV_SQRT_D * __expf(-0.1f * fminf(fd, 5.0f)) - 0.1f * fd;
  }

  const u16* qbase = qh + (size_t)(b * SEQ + bm) * HID + hh * 192;
  const u16* kbase = kh + (size_t)b * SEQ * HID + hh * 192;
  const u16* vbase = vTh + (size_t)b * HID * SEQ + (size_t)(hh * 192) * SEQ;

  // Q fragments in registers (A-operand, identical for all waves)
  h8v qf[2][6];
#pragma unroll
  for (int i = 0; i < 2; ++i)
#pragma unroll
    for (int ks = 0; ks < 6; ++ks)
      qf[i][ks] = *(const h8v*)(qbase + (size_t)(i * 16 + ml) * HID + ks * 32 + quad * 8);

  // staging decomposition: 1536 8-u16 chunks each for K_j and vT_j
  int koff[6], kldso[6], voff[6], vldso[6];
#pragma unroll
  for (int c = 0; c < 6; ++c) {
    const int cc = c * 256 + tid;
    const int krow = cc / 24, kcol = cc % 24;      // K_j: [64 rows][24 chunks]
    koff[c]  = krow * HID + kcol * 8;
    kldso[c] = krow * 200 + kcol * 8;
    const int vrow = cc >> 3, vcol = cc & 7;       // vT_j: [192 rows][8 chunks]
    voff[c]  = vrow * SEQ + vcol * 8;
    vldso[c] = 12800 + vrow * 72 + vcol * 8;
  }
  s8v kc[6], vc[6];
#pragma unroll
  for (int c = 0; c < 6; ++c) {
    kc[c] = *(const s8v*)(kbase + koff[c]);
    vc[c] = *(const s8v*)(vbase + voff[c]);
  }

  f4v acc2[2][3];
#pragma unroll
  for (int i = 0; i < 2; ++i)
#pragma unroll
    for (int jj = 0; jj < 3; ++jj) acc2[i][jj] = (f4v)0.f;
  float rsum[2][4];
#pragma unroll
  for (int i = 0; i < 2; ++i)
#pragma unroll
    for (int r = 0; r < 4; ++r) rsum[i][r] = 0.f;

  for (int j = 0; j < 8; ++j) {
    __syncthreads();                       // b1: prev-iter LDS reads done
#pragma unroll
    for (int c = 0; c < 6; ++c) {
      *(s8v*)&lds[kldso[c]] = kc[c];
      *(s8v*)&lds[vldso[c]] = vc[c];
    }
    __syncthreads();                       // b2: K_j/vT_j (+gtab, j==0) visible
    if (j < 7) {                           // prefetch next K-block into regs
      const int ko = (j + 1) * 64;
#pragma unroll
      for (int c = 0; c < 6; ++c) {
        kc[c] = *(const s8v*)(kbase + (size_t)ko * HID + koff[c]);
        vc[c] = *(const s8v*)(vbase + ko + voff[c]);
      }
    }
    // ---- QK^T: 12 MFMA ----
    f4v sacc[2];
    sacc[0] = (f4v)0.f; sacc[1] = (f4v)0.f;
    __builtin_amdgcn_s_setprio(1);
#pragma unroll
    for (int ks = 0; ks < 6; ++ks) {
      const h8v kf = *(const h8v*)&lds[(w * 16 + ml) * 200 + ks * 32 + quad * 8];
      sacc[0] = __builtin_amdgcn_mfma_f32_16x16x32_f16(qf[0][ks], kf, sacc[0], 0, 0, 0);
      sacc[1] = __builtin_amdgcn_mfma_f32_16x16x32_f16(qf[1][ks], kf, sacc[1], 0, 0, 0);
    }
    __builtin_amdgcn_s_setprio(0);
    // ---- transform + P write (max-free exp; 1 exp/elem via g-table) ----
    const int scolg = j * 64 + w * 16 + ml;
#pragma unroll
    for (int i = 0; i < 2; ++i)
#pragma unroll
      for (int r = 0; r < 4; ++r) {
        const int lrow = i * 16 + quad * 4 + r;
        const float g = gtab[bm + lrow - scolg + 511];
        const float p = __expf(fmaf(sacc[i][r], INV_SQRT_D, g));
        rsum[i][r] += p;
        lds[26624 + lrow * 72 + w * 16 + ml] = f2h(p);
      }
    __syncthreads();                       // b3: P_j visible
    // ---- PV: 12 MFMA ----
    __builtin_amdgcn_s_setprio(1);
#pragma unroll
    for (int ks = 0; ks < 2; ++ks) {
      h8v pf[2], vf[3];
#pragma unroll
      for (int i = 0; i < 2; ++i)
        pf[i] = *(const h8v*)&lds[26624 + (i * 16 + ml) * 72 + ks * 32 + quad * 8];
#pragma unroll
      for (int jj = 0; jj < 3; ++jj)
        vf[jj] = *(const h8v*)&lds[12800 + (w * 48 + jj * 16 + ml) * 72 + ks * 32 + quad * 8];
#pragma unroll
      for (int i = 0; i < 2; ++i)
#pragma unroll
        for (int jj = 0; jj < 3; ++jj)
          acc2[i][jj] = __builtin_amdgcn_mfma_f32_16x16x32_f16(pf[i], vf[jj], acc2[i][jj], 0, 0, 0);
    }
    __builtin_amdgcn_s_setprio(0);
  }

  // ---- final row-sum reduce (single barrier) ----
#pragma unroll
  for (int i = 0; i < 2; ++i)
#pragma unroll
    for (int r = 0; r < 4; ++r) {
      float t = rsum[i][r];
#pragma unroll
      for (int o = 1; o < 16; o <<= 1) t += __shfl_xor(t, o, 64);
      rsum[i][r] = t;
    }
  if (ml == 0) {
#pragma unroll
    for (int i = 0; i < 2; ++i)
#pragma unroll
      for (int r = 0; r < 4; ++r) red[w][i * 16 + quad * 4 + r] = rsum[i][r];
  }
  __syncthreads();

  // ---- ctx out (normalize here) ----
#pragma unroll
  for (int i = 0; i < 2; ++i)
#pragma unroll
    for (int r = 0; r < 4; ++r) {
      const int R = i * 16 + quad * 4 + r;
      const float is = 1.0f / (red[0][R] + red[1][R] + red[2][R] + red[3][R]);
      const int m = bm + R;
#pragma unroll
      for (int jj = 0; jj < 3; ++jj) {
        const int gcol = hh * 192 + w * 48 + jj * 16 + ml;
        ch[(size_t)(b * SEQ + m) * HID + gcol] = f2h(acc2[i][jj][r] * is);
      }
    }
}

// ---- projection GEMM + bias + residual -> h fp32 (XCD-swizzled, gll fp16) ----
__global__ __launch_bounds__(256, 3) void proj_mm(
    const u16* __restrict__ ch, const u16* __restrict__ WTh,
    const float* __restrict__ bo, const float* __restrict__ x, float* __restrict__ h)
{
  __shared__ u16 lds[16384];
  const int id = blockIdx.x;
  const int xcd = id & 7;
  const int s = id >> 3;            // 0..47
  const int bx = s % 6;
  const int yl = s / 6;             // 0..7
  const int bm = (yl * 8 + xcd) * 128;
  const int bn = bx * 128;
  const size_t wtoff = (size_t)3 * HID * HID + (size_t)bn * HID;
  f4v acc[4][4];
#pragma unroll
  for (int i = 0; i < 4; ++i)
#pragma unroll
    for (int j = 0; j < 4; ++j) acc[i][j] = (f4v)0.f;
  mm_core128<24>(ch + (size_t)bm * HID, HID, WTh + wtoff, HID, lds, acc);
  const int tid = threadIdx.x, w = tid >> 6, ln = tid & 63;
  const int ml = ln & 15, quad = ln >> 4;
  const int wr = (w >> 1) * 64, wc = (w & 1) * 64;
#pragma unroll
  for (int i = 0; i < 4; ++i)
#pragma unroll
    for (int j = 0; j < 4; ++j) {
      const int gcol = bn + wc + j * 16 + ml;
      const float bv_ = bo[gcol];
#pragma unroll
      for (int r = 0; r < 4; ++r) {
        const int grow = bm + wr + i * 16 + quad * 4 + r;
        const size_t idx = (size_t)grow * HID + gcol;
        h[idx] = acc[i][j][r] + bv_ + x[idx];
      }
    }
}

// ---- LayerNorm + 9-label classifier ----
__global__ __launch_bounds__(256) void ln_logits_kernel(
    const float* __restrict__ h, const float* __restrict__ g,
    const float* __restrict__ bta, const float* __restrict__ Ws,
    const float* __restrict__ bsv, float* __restrict__ span)
{
  const int row = blockIdx.x;
  const int tid = threadIdx.x;
  const float* hr = h + (size_t)row * HID;
  const float x0 = hr[tid], x1 = hr[tid + 256], x2 = hr[tid + 512];
  float s = x0 + x1 + x2;
  float sq = x0 * x0 + x1 * x1 + x2 * x2;
#pragma unroll
  for (int o = 32; o > 0; o >>= 1) { s += __shfl_down(s, o, 64); sq += __shfl_down(sq, o, 64); }
  __shared__ float red[8];
  __shared__ float smu, srs;
  const int wid = tid >> 6, lid = tid & 63;
  if (lid == 0) { red[wid] = s; red[4 + wid] = sq; }
  __syncthreads();
  if (tid == 0) {
    const float ts = red[0] + red[1] + red[2] + red[3];
    const float tq = red[4] + red[5] + red[6] + red[7];
    const float mu = ts / 768.0f;
    const float var = tq / 768.0f - mu * mu;
    smu = mu; srs = rsqrtf(var + 1e-5f);
  }
  __syncthreads();
  const float mu = smu, rs = srs;
  const float n0 = (x0 - mu) * rs * g[tid] + bta[tid];
  const float n1 = (x1 - mu) * rs * g[tid + 256] + bta[tid + 256];
  const float n2 = (x2 - mu) * rs * g[tid + 512] + bta[tid + 512];
  float pl[9];
#pragma unroll
  for (int l = 0; l < 9; ++l)
    pl[l] = n0 * Ws[(size_t)tid * 9 + l]
          + n1 * Ws[(size_t)(tid + 256) * 9 + l]
          + n2 * Ws[(size_t)(tid + 512) * 9 + l];
#pragma unroll
  for (int l = 0; l < 9; ++l)
#pragma unroll
    for (int o = 32; o > 0; o >>= 1) pl[l] += __shfl_down(pl[l], o, 64);
  __shared__ float lred[4][9];
  if (lid == 0) {
#pragma unroll
    for (int l = 0; l < 9; ++l) lred[wid][l] = pl[l];
  }
  __syncthreads();
  if (tid < 9) {
    span[(size_t)row * 9 + tid] =
        lred[0][tid] + lred[1][tid] + lred[2][tid] + lred[3][tid] + bsv[tid];
  }
}

// ---- entity-bias bump ----
__global__ __launch_bounds__(256) void bump_kernel(
    const float* __restrict__ span, const float* __restrict__ eb, float* __restrict__ out)
{
  const int idx = blockIdx.x * 256 + threadIdx.x;
  if (idx >= ROWS) return;
  const int j = idx & (SEQ - 1);
  const float* sl = span + (size_t)idx * 9;
  float v[9];
#pragma unroll
  for (int l = 0; l < 9; ++l) v[l] = sl[l];
  if (j >= 1) {
    const float* sp = sl - 9;
    float m = sp[0]; int am = 0;
#pragma unroll
    for (int l = 1; l < 9; ++l) { const float t = sp[l]; if (t > m) { m = t; am = l; } }
    if (am == 1) v[2] += 2.0f * eb[2];
  }
#pragma unroll
  for (int l = 0; l < 9; ++l) out[(size_t)idx * 9 + l] = v[l];
}

extern "C" void kernel_launch(void* const* d_in, const int* in_sizes, int n_in,
                              void* d_out, int out_size, void* d_ws, size_t ws_size,
                              hipStream_t stream)
{
  (void)in_sizes; (void)n_in; (void)out_size; (void)ws_size;
  const float* x   = (const float*)d_in[0];
  const float* Wq  = (const float*)d_in[1];
  const float* bq  = (const float*)d_in[2];
  const float* Wk  = (const float*)d_in[3];
  const float* bk  = (const float*)d_in[4];
  const float* Wv  = (const float*)d_in[5];
  const float* bv  = (const float*)d_in[6];
  const float* Wo  = (const float*)d_in[7];
  const float* bo  = (const float*)d_in[8];
  const float* lng = (const float*)d_in[9];
  const float* lnb = (const float*)d_in[10];
  const float* Ws  = (const float*)d_in[11];
  const float* bs  = (const float*)d_in[12];
  const float* eb  = (const float*)d_in[13];
  float* out = (float*)d_out;

  char* ws = (char*)d_ws;
  u16* xh  = (u16*)(ws + 0);                       // fp16 x (12.6MB)
  u16* WTh = (u16*)(ws + 25165824);                // fp16 WT (4 matrices)
  u16* qh  = (u16*)(ws + 34603008);
  u16* kh  = (u16*)(ws + 59768832);
  u16* vTh = (u16*)(ws + 84934656);                // fp16 vT (12.6MB)
  float* hb = (float*)(ws + 84934656);             // fp32 h (25MB, overwrites vT after attn)
  float* spanb = (float*)(ws + 152043520);
  u16* ctxh = qh;                                  // q dead after attn

  splitx<<<dim3(1572864 / 256), 256, 0, stream>>>(x, xh);
  wsplit<<<dim3(24, 24, 4), 256, 0, stream>>>(Wq, Wk, Wv, Wo, WTh);
  qkv_mm<<<dim3(1152), 256, 0, stream>>>(xh, WTh, bq, bk, bv, qh, kh, vTh);
  attn_fused<<<dim3(1024), 256, 0, stream>>>(qh, kh, vTh, ctxh);
  proj_mm<<<dim3(384), 256, 0, stream>>>(ctxh, WTh, bo, x, hb);
  ln_logits_kernel<<<dim3(ROWS), 256, 0, stream>>>(hb, lng, lnb, Ws, bs, spanb);
  bump_kernel<<<dim3(ROWS / 256), 256, 0, stream>>>(spanb, eb, out);
}

// Round 4
// 219.100 us; speedup vs baseline: 1.1799x; 1.0350x over previous
//
#include <hip/hip_runtime.h>
#include <math.h>

#define SEQ 512
#define HID 768
#define NBATCH 16
#define ROWS 8192
#define INV_SQRT_D 0.07216878364870323f

typedef short s8v __attribute__((ext_vector_type(8)));
typedef _Float16 h8v __attribute__((ext_vector_type(8)));
typedef float f4v __attribute__((ext_vector_type(4)));
typedef unsigned short u16;

// ---- fp16 helper (RNE) ----
__device__ __forceinline__ u16 f2h(float f) {
  _Float16 h = (_Float16)f;
  return __builtin_bit_cast(u16, h);
}

// ---- async global->LDS 16B copy (m97/m151: 1.35x over reg-staging) ----
// LDS dest must be wave-uniform base (HW adds lane*16); global src is per-lane.
__device__ __forceinline__ void llds16(const u16* g, u16* l) {
  __builtin_amdgcn_global_load_lds(
      (const __attribute__((address_space(1))) void*)g,
      (__attribute__((address_space(3))) void*)l, 16, 0, 0);
}

// ---------------------------------------------------------------------------
// fp16 GEMM core (R13): BK=64 via paired 32-wide sub-tiles, staged with
// global_load_lds (direct-to-LDS DMA). Source address carries the csw
// pre-swizzle (m173 pattern: pre-swizzled global + linear-in-lane LDS dest);
// fragment reads keep the fo2 swizzle (conflict-free b128).
// LDS 32KB: sub0 {A@0,B@4096}, sub1 {A@8192,B@12288} (u16 idx).
// ---------------------------------------------------------------------------
template <int KSTEPS>   // number of 32-wide steps; must be even
__device__ __forceinline__ void mm_core128(
    const u16* __restrict__ A, const int lda,
    const u16* __restrict__ B, const int ldb,
    u16* lds, f4v (&acc)[4][4])
{
  const int tid = threadIdx.x;
  const int w = tid >> 6, ln = tid & 63;
  const u16* src = (w >> 1) ? B : A;
  const int ld = (w >> 1) ? ldb : lda;
  const int half = w & 1;
  const int srow = ln >> 2;
  const int csw  = ((ln & 3) - (ln >> 3)) & 3;
  const int ml = ln & 15;
  const int fo2 = (((ln >> 4) + ((ln >> 1) & 3)) & 3) * 8;
  const int wr = (w >> 1) * 64, wc = (w & 1) * 64;

  const u16* gp[4];
  u16* lp[4];
#pragma unroll
  for (int t = 0; t < 4; ++t) {
    const int row = half * 64 + t * 16 + srow;
    gp[t] = src + (size_t)row * ld + csw * 8;
    lp[t] = lds + (w >> 1) * 4096 + half * 2048 + t * 512;   // wave-uniform
  }

  for (int kp = 0; kp < KSTEPS / 2; ++kp) {
    const int k0 = kp * 64;
    __syncthreads();                       // prev-iter LDS reads done
#pragma unroll
    for (int t = 0; t < 4; ++t) {
      llds16(gp[t] + k0,      lp[t]);
      llds16(gp[t] + k0 + 32, lp[t] + 8192);
    }
    __syncthreads();                       // vmcnt(0) drain + visibility
#pragma unroll
    for (int sub = 0; sub < 2; ++sub) {
      const int so = sub * 8192;
      h8v a[4], b[4];
#pragma unroll
      for (int i = 0; i < 4; ++i)
        a[i] = *(const h8v*)&lds[so + (wr + i * 16 + ml) * 32 + fo2];
#pragma unroll
      for (int j = 0; j < 4; ++j)
        b[j] = *(const h8v*)&lds[so + 4096 + (wc + j * 16 + ml) * 32 + fo2];
#pragma unroll
      for (int i = 0; i < 4; ++i)
#pragma unroll
        for (int j = 0; j < 4; ++j)
          acc[i][j] = __builtin_amdgcn_mfma_f32_16x16x32_f16(a[i], b[j], acc[i][j], 0, 0, 0);
    }
  }
}

// ---- prep: x -> fp16 ----
__global__ __launch_bounds__(256) void splitx(const float* __restrict__ x,
                                              u16* __restrict__ xh)
{
  const int i = blockIdx.x * 256 + threadIdx.x;
  const float4 v = ((const float4*)x)[i];
  ((ushort4*)xh)[i] = make_ushort4(f2h(v.x), f2h(v.y), f2h(v.z), f2h(v.w));
}

// ---- prep: transpose weights: WT[z][n][k] = W_z[k][n], fp16 ----
__global__ __launch_bounds__(256) void wsplit(
    const float* __restrict__ Wq, const float* __restrict__ Wk,
    const float* __restrict__ Wv, const float* __restrict__ Wo,
    u16* __restrict__ WTh)
{
  __shared__ float t[32][33];
  const int z = blockIdx.z;
  const float* W = (z == 0) ? Wq : (z == 1) ? Wk : (z == 2) ? Wv : Wo;
  const int n0 = blockIdx.x * 32, k0 = blockIdx.y * 32;
  const int tx = threadIdx.x & 31, ty = threadIdx.x >> 5;
#pragma unroll
  for (int i = 0; i < 4; ++i)
    t[ty + 8 * i][tx] = W[(size_t)(k0 + ty + 8 * i) * HID + n0 + tx];
  __syncthreads();
#pragma unroll
  for (int i = 0; i < 4; ++i) {
    const float v = t[tx][ty + 8 * i];
    const size_t idx = (size_t)z * HID * HID + (size_t)(n0 + ty + 8 * i) * HID + k0 + tx;
    WTh[idx] = f2h(v);
  }
}

// ---- QKV GEMM, XCD-swizzled 1D grid (1152 blocks), gll fp16 BK=64 core.
//      z==2 (v): transpose through LDS, coalesced 16B vT stores (R14 fix for
//      the R13 64-lane 8B scatter at 1KB stride). ----
__global__ __launch_bounds__(256, 3) void qkv_mm(
    const u16* __restrict__ xh, const u16* __restrict__ WTh,
    const float* __restrict__ bq, const float* __restrict__ bk, const float* __restrict__ bv,
    u16* __restrict__ qh, u16* __restrict__ kh, u16* __restrict__ vTh)
{
  __shared__ u16 lds[17408];        // 16384 for mm_core; 17408 for vT transpose
  const int id = blockIdx.x;
  const int xcd = id & 7;
  const int s = id >> 3;            // 0..143
  const int bx = s % 6;
  const int yl = (s / 6) & 7;
  const int z  = s / 48;
  const int bm = (yl * 8 + xcd) * 128;
  const int bn = bx * 128;
  const size_t wtoff = (size_t)z * HID * HID + (size_t)bn * HID;
  f4v acc[4][4];
#pragma unroll
  for (int i = 0; i < 4; ++i)
#pragma unroll
    for (int j = 0; j < 4; ++j) acc[i][j] = (f4v)0.f;
  mm_core128<24>(xh + (size_t)bm * HID, HID, WTh + wtoff, HID, lds, acc);
  const int tid = threadIdx.x, w = tid >> 6, ln = tid & 63;
  const int ml = ln & 15, quad = ln >> 4;
  const int wr = (w >> 1) * 64, wc = (w & 1) * 64;
  if (z == 2) {
    // transpose via LDS: lds[n_local*136 + seq_local], then coalesced out
    __syncthreads();                       // mm_core's last LDS reads done
#pragma unroll
    for (int i = 0; i < 4; ++i)
#pragma unroll
      for (int j = 0; j < 4; ++j) {
        const int ncol = wc + j * 16 + ml;
        const float bv_ = bv[bn + ncol];
#pragma unroll
        for (int r = 0; r < 4; ++r) {
          const int srow = wr + i * 16 + quad * 4 + r;
          lds[ncol * 136 + srow] = f2h(acc[i][j][r] + bv_);
        }
      }
    __syncthreads();
    u16* vb = vTh + (size_t)(bm >> 9) * HID * SEQ;
    const int sq0 = bm & 511;
    const int c8 = (tid & 15) * 8;
#pragma unroll
    for (int p = 0; p < 8; ++p) {
      const int nl = p * 16 + (tid >> 4);  // 0..127
      const s8v val = *(const s8v*)&lds[nl * 136 + c8];
      *(s8v*)&vb[(size_t)(bn + nl) * SEQ + sq0 + c8] = val;
    }
  } else {
    const float* bias = (z == 0) ? bq : bk;
    u16* dst = (z == 0) ? qh : kh;
#pragma unroll
    for (int i = 0; i < 4; ++i)
#pragma unroll
      for (int j = 0; j < 4; ++j) {
        const int gcol = bn + wc + j * 16 + ml;
        const float bv_ = bias[gcol];
#pragma unroll
        for (int r = 0; r < 4; ++r) {
          const int grow = bm + wr + i * 16 + quad * 4 + r;
          dst[(size_t)grow * HID + gcol] = f2h(acc[i][j][r] + bv_);
        }
      }
  }
}

// ---------------------------------------------------------------------------
// FLASH attention v4 (R14): 64 Q-rows per block -> 512 blocks = exactly
// 2 blocks/CU x 256 CU, ONE resident round (was 2), zero tail. Same K/V
// staging per iteration now feeds 96 MFMA (was 48): wave = (row-half rh,
// col-half ch2); QK^T 24 MFMA/wave, PV 24 MFMA/wave, 3 barriers/iter.
// Max-free softmax via g-table (exact; validated R11-R13). One sum-reduce
// at the end. Grid XCD-bijective: 8 (b,h) per XCD -> K+V 3.1MB < 4MB L2.
// LDS: KT[64][200]@0, VT[192][72]@12800, PT[64][72]@26624 = 62.5KB
// (+gtab 4KB +red 0.5KB) -> 2 blocks/CU.
// ---------------------------------------------------------------------------
__global__ __launch_bounds__(256, 2) void attn_fused(
    const u16* __restrict__ qh, const u16* __restrict__ kh,
    const u16* __restrict__ vTh, u16* __restrict__ ch)
{
  __shared__ u16 lds[31232];
  __shared__ float gtab[1024];
  __shared__ float red[4][32];
  const int f = blockIdx.x;            // 512 blocks
  const int xcd = f & 7, s = f >> 3;   // s: 0..63
  const int z = xcd * 8 + (s >> 3);    // (b,h) 0..63, 8 per XCD
  const int bm = (s & 7) * 64;
  const int b = z >> 2, hh = z & 3;
  const int tid = threadIdx.x, w = tid >> 6, ln = tid & 63;
  const int ml = ln & 15, quad = ln >> 4;
  const int rh = w >> 1, ch2 = w & 1;  // row-half / col-half of the wave

  // g-table: idx = (srow - scol) + 511
  for (int t = tid; t < 1023; t += 256) {
    const float fd = fabsf((float)(t - 511));
    gtab[t] = INV_SQRT_D * __expf(-0.1f * fminf(fd, 5.0f)) - 0.1f * fd;
  }

  const u16* qbase = qh + (size_t)(b * SEQ + bm + rh * 32) * HID + hh * 192;
  const u16* kbase = kh + (size_t)b * SEQ * HID + hh * 192;
  const u16* vbase = vTh + (size_t)b * HID * SEQ + (size_t)(hh * 192) * SEQ;

  // Q fragments in registers (wave's 32 rows)
  h8v qf[2][6];
#pragma unroll
  for (int i = 0; i < 2; ++i)
#pragma unroll
    for (int ks = 0; ks < 6; ++ks)
      qf[i][ks] = *(const h8v*)(qbase + (size_t)(i * 16 + ml) * HID + ks * 32 + quad * 8);

  // staging decomposition: 1536 8-u16 chunks each for K_j and vT_j
  int koff[6], kldso[6], voff[6], vldso[6];
#pragma unroll
  for (int c = 0; c < 6; ++c) {
    const int cc = c * 256 + tid;
    const int krow = cc / 24, kcol = cc % 24;      // K_j: [64 rows][24 chunks]
    koff[c]  = krow * HID + kcol * 8;
    kldso[c] = krow * 200 + kcol * 8;
    const int vrow = cc >> 3, vcol = cc & 7;       // vT_j: [192 rows][8 chunks]
    voff[c]  = vrow * SEQ + vcol * 8;
    vldso[c] = 12800 + vrow * 72 + vcol * 8;
  }
  s8v kc[6], vc[6];
#pragma unroll
  for (int c = 0; c < 6; ++c) {
    kc[c] = *(const s8v*)(kbase + koff[c]);
    vc[c] = *(const s8v*)(vbase + voff[c]);
  }

  f4v acc2[2][6];
#pragma unroll
  for (int i = 0; i < 2; ++i)
#pragma unroll
    for (int jj = 0; jj < 6; ++jj) acc2[i][jj] = (f4v)0.f;
  float rsum[2][4];
#pragma unroll
  for (int i = 0; i < 2; ++i)
#pragma unroll
    for (int r = 0; r < 4; ++r) rsum[i][r] = 0.f;

  for (int j = 0; j < 8; ++j) {
    __syncthreads();                       // b1: prev-iter LDS reads done
#pragma unroll
    for (int c = 0; c < 6; ++c) {
      *(s8v*)&lds[kldso[c]] = kc[c];
      *(s8v*)&lds[vldso[c]] = vc[c];
    }
    __syncthreads();                       // b2: K_j/vT_j (+gtab, j==0) visible
    if (j < 7) {                           // prefetch next K-block into regs
      const int ko = (j + 1) * 64;
#pragma unroll
      for (int c = 0; c < 6; ++c) {
        kc[c] = *(const s8v*)(kbase + (size_t)ko * HID + koff[c]);
        vc[c] = *(const s8v*)(vbase + ko + voff[c]);
      }
    }
    // ---- QK^T: 24 MFMA/wave (64Q x 32K per wave) ----
    f4v sacc[2][2];
    sacc[0][0] = (f4v)0.f; sacc[0][1] = (f4v)0.f;
    sacc[1][0] = (f4v)0.f; sacc[1][1] = (f4v)0.f;
    __builtin_amdgcn_s_setprio(1);
#pragma unroll
    for (int ks = 0; ks < 6; ++ks) {
      h8v kf0 = *(const h8v*)&lds[(ch2 * 32 + ml) * 200 + ks * 32 + quad * 8];
      h8v kf1 = *(const h8v*)&lds[(ch2 * 32 + 16 + ml) * 200 + ks * 32 + quad * 8];
      sacc[0][0] = __builtin_amdgcn_mfma_f32_16x16x32_f16(qf[0][ks], kf0, sacc[0][0], 0, 0, 0);
      sacc[1][0] = __builtin_amdgcn_mfma_f32_16x16x32_f16(qf[1][ks], kf0, sacc[1][0], 0, 0, 0);
      sacc[0][1] = __builtin_amdgcn_mfma_f32_16x16x32_f16(qf[0][ks], kf1, sacc[0][1], 0, 0, 0);
      sacc[1][1] = __builtin_amdgcn_mfma_f32_16x16x32_f16(qf[1][ks], kf1, sacc[1][1], 0, 0, 0);
    }
    __builtin_amdgcn_s_setprio(0);
    // ---- transform + P write (max-free exp; 1 exp/elem via g-table) ----
#pragma unroll
    for (int i = 0; i < 2; ++i)
#pragma unroll
      for (int j2 = 0; j2 < 2; ++j2) {
        const int lcol = ch2 * 32 + j2 * 16 + ml;
        const int scolg = j * 64 + lcol;
#pragma unroll
        for (int r = 0; r < 4; ++r) {
          const int lrow = rh * 32 + i * 16 + quad * 4 + r;
          const float g = gtab[bm + lrow - scolg + 511];
          const float p = __expf(fmaf(sacc[i][j2][r], INV_SQRT_D, g));
          rsum[i][r] += p;
          lds[26624 + lrow * 72 + lcol] = f2h(p);
        }
      }
    __syncthreads();                       // b3: P_j visible
    // ---- PV: 24 MFMA/wave (64Q x 96 head-dims per wave) ----
    __builtin_amdgcn_s_setprio(1);
#pragma unroll
    for (int ks = 0; ks < 2; ++ks) {
      h8v pf[2], vf[6];
#pragma unroll
      for (int i = 0; i < 2; ++i)
        pf[i] = *(const h8v*)&lds[26624 + (rh * 32 + i * 16 + ml) * 72 + ks * 32 + quad * 8];
#pragma unroll
      for (int jj = 0; jj < 6; ++jj)
        vf[jj] = *(const h8v*)&lds[12800 + (ch2 * 96 + jj * 16 + ml) * 72 + ks * 32 + quad * 8];
#pragma unroll
      for (int i = 0; i < 2; ++i)
#pragma unroll
        for (int jj = 0; jj < 6; ++jj)
          acc2[i][jj] = __builtin_amdgcn_mfma_f32_16x16x32_f16(pf[i], vf[jj], acc2[i][jj], 0, 0, 0);
    }
    __builtin_amdgcn_s_setprio(0);
  }

  // ---- final row-sum reduce ----
#pragma unroll
  for (int i = 0; i < 2; ++i)
#pragma unroll
    for (int r = 0; r < 4; ++r) {
      float t = rsum[i][r];
#pragma unroll
      for (int o = 1; o < 16; o <<= 1) t += __shfl_xor(t, o, 64);
      rsum[i][r] = t;
    }
  if (ml == 0) {
#pragma unroll
    for (int i = 0; i < 2; ++i)
#pragma unroll
      for (int r = 0; r < 4; ++r) red[w][i * 16 + quad * 4 + r] = rsum[i][r];
  }
  __syncthreads();

  // ---- ctx out (normalize here) ----
#pragma unroll
  for (int i = 0; i < 2; ++i)
#pragma unroll
    for (int r = 0; r < 4; ++r) {
      const int lr = i * 16 + quad * 4 + r;
      const float is = 1.0f / (red[rh * 2][lr] + red[rh * 2 + 1][lr]);
      const int m = bm + rh * 32 + lr;
#pragma unroll
      for (int jj = 0; jj < 6; ++jj) {
        const int gcol = hh * 192 + ch2 * 96 + jj * 16 + ml;
        ch[(size_t)(b * SEQ + m) * HID + gcol] = f2h(acc2[i][jj][r] * is);
      }
    }
}

// ---- projection GEMM + bias + residual -> h fp32 (XCD-swizzled, gll fp16) ----
__global__ __launch_bounds__(256, 3) void proj_mm(
    const u16* __restrict__ ch, const u16* __restrict__ WTh,
    const float* __restrict__ bo, const float* __restrict__ x, float* __restrict__ h)
{
  __shared__ u16 lds[16384];
  const int id = blockIdx.x;
  const int xcd = id & 7;
  const int s = id >> 3;            // 0..47
  const int bx = s % 6;
  const int yl = s / 6;             // 0..7
  const int bm = (yl * 8 + xcd) * 128;
  const int bn = bx * 128;
  const size_t wtoff = (size_t)3 * HID * HID + (size_t)bn * HID;
  f4v acc[4][4];
#pragma unroll
  for (int i = 0; i < 4; ++i)
#pragma unroll
    for (int j = 0; j < 4; ++j) acc[i][j] = (f4v)0.f;
  mm_core128<24>(ch + (size_t)bm * HID, HID, WTh + wtoff, HID, lds, acc);
  const int tid = threadIdx.x, w = tid >> 6, ln = tid & 63;
  const int ml = ln & 15, quad = ln >> 4;
  const int wr = (w >> 1) * 64, wc = (w & 1) * 64;
#pragma unroll
  for (int i = 0; i < 4; ++i)
#pragma unroll
    for (int j = 0; j < 4; ++j) {
      const int gcol = bn + wc + j * 16 + ml;
      const float bv_ = bo[gcol];
#pragma unroll
      for (int r = 0; r < 4; ++r) {
        const int grow = bm + wr + i * 16 + quad * 4 + r;
        const size_t idx = (size_t)grow * HID + gcol;
        h[idx] = acc[i][j][r] + bv_ + x[idx];
      }
    }
}

// ---- LayerNorm + 9-label classifier ----
__global__ __launch_bounds__(256) void ln_logits_kernel(
    const float* __restrict__ h, const float* __restrict__ g,
    const float* __restrict__ bta, const float* __restrict__ Ws,
    const float* __restrict__ bsv, float* __restrict__ span)
{
  const int row = blockIdx.x;
  const int tid = threadIdx.x;
  const float* hr = h + (size_t)row * HID;
  const float x0 = hr[tid], x1 = hr[tid + 256], x2 = hr[tid + 512];
  float s = x0 + x1 + x2;
  float sq = x0 * x0 + x1 * x1 + x2 * x2;
#pragma unroll
  for (int o = 32; o > 0; o >>= 1) { s += __shfl_down(s, o, 64); sq += __shfl_down(sq, o, 64); }
  __shared__ float red[8];
  __shared__ float smu, srs;
  const int wid = tid >> 6, lid = tid & 63;
  if (lid == 0) { red[wid] = s; red[4 + wid] = sq; }
  __syncthreads();
  if (tid == 0) {
    const float ts = red[0] + red[1] + red[2] + red[3];
    const float tq = red[4] + red[5] + red[6] + red[7];
    const float mu = ts / 768.0f;
    const float var = tq / 768.0f - mu * mu;
    smu = mu; srs = rsqrtf(var + 1e-5f);
  }
  __syncthreads();
  const float mu = smu, rs = srs;
  const float n0 = (x0 - mu) * rs * g[tid] + bta[tid];
  const float n1 = (x1 - mu) * rs * g[tid + 256] + bta[tid + 256];
  const float n2 = (x2 - mu) * rs * g[tid + 512] + bta[tid + 512];
  float pl[9];
#pragma unroll
  for (int l = 0; l < 9; ++l)
    pl[l] = n0 * Ws[(size_t)tid * 9 + l]
          + n1 * Ws[(size_t)(tid + 256) * 9 + l]
          + n2 * Ws[(size_t)(tid + 512) * 9 + l];
#pragma unroll
  for (int l = 0; l < 9; ++l)
#pragma unroll
    for (int o = 32; o > 0; o >>= 1) pl[l] += __shfl_down(pl[l], o, 64);
  __shared__ float lred[4][9];
  if (lid == 0) {
#pragma unroll
    for (int l = 0; l < 9; ++l) lred[wid][l] = pl[l];
  }
  __syncthreads();
  if (tid < 9) {
    span[(size_t)row * 9 + tid] =
        lred[0][tid] + lred[1][tid] + lred[2][tid] + lred[3][tid] + bsv[tid];
  }
}

// ---- entity-bias bump ----
__global__ __launch_bounds__(256) void bump_kernel(
    const float* __restrict__ span, const float* __restrict__ eb, float* __restrict__ out)
{
  const int idx = blockIdx.x * 256 + threadIdx.x;
  if (idx >= ROWS) return;
  const int j = idx & (SEQ - 1);
  const float* sl = span + (size_t)idx * 9;
  float v[9];
#pragma unroll
  for (int l = 0; l < 9; ++l) v[l] = sl[l];
  if (j >= 1) {
    const float* sp = sl - 9;
    float m = sp[0]; int am = 0;
#pragma unroll
    for (int l = 1; l < 9; ++l) { const float t = sp[l]; if (t > m) { m = t; am = l; } }
    if (am == 1) v[2] += 2.0f * eb[2];
  }
#pragma unroll
  for (int l = 0; l < 9; ++l) out[(size_t)idx * 9 + l] = v[l];
}

extern "C" void kernel_launch(void* const* d_in, const int* in_sizes, int n_in,
                              void* d_out, int out_size, void* d_ws, size_t ws_size,
                              hipStream_t stream)
{
  (void)in_sizes; (void)n_in; (void)out_size; (void)ws_size;
  const float* x   = (const float*)d_in[0];
  const float* Wq  = (const float*)d_in[1];
  const float* bq  = (const float*)d_in[2];
  const float* Wk  = (const float*)d_in[3];
  const float* bk  = (const float*)d_in[4];
  const float* Wv  = (const float*)d_in[5];
  const float* bv  = (const float*)d_in[6];
  const float* Wo  = (const float*)d_in[7];
  const float* bo  = (const float*)d_in[8];
  const float* lng = (const float*)d_in[9];
  const float* lnb = (const float*)d_in[10];
  const float* Ws  = (const float*)d_in[11];
  const float* bs  = (const float*)d_in[12];
  const float* eb  = (const float*)d_in[13];
  float* out = (float*)d_out;

  char* ws = (char*)d_ws;
  u16* xh  = (u16*)(ws + 0);                       // fp16 x (12.6MB)
  u16* WTh = (u16*)(ws + 25165824);                // fp16 WT (4 matrices)
  u16* qh  = (u16*)(ws + 34603008);
  u16* kh  = (u16*)(ws + 59768832);
  u16* vTh = (u16*)(ws + 84934656);                // fp16 vT (12.6MB)
  float* hb = (float*)(ws + 84934656);             // fp32 h (25MB, overwrites vT after attn)
  float* spanb = (float*)(ws + 152043520);
  u16* ctxh = qh;                                  // q dead after attn

  splitx<<<dim3(1572864 / 256), 256, 0, stream>>>(x, xh);
  wsplit<<<dim3(24, 24, 4), 256, 0, stream>>>(Wq, Wk, Wv, Wo, WTh);
  qkv_mm<<<dim3(1152), 256, 0, stream>>>(xh, WTh, bq, bk, bv, qh, kh, vTh);
  attn_fused<<<dim3(512), 256, 0, stream>>>(qh, kh, vTh, ctxh);
  proj_mm<<<dim3(384), 256, 0, stream>>>(ctxh, WTh, bo, x, hb);
  ln_logits_kernel<<<dim3(ROWS), 256, 0, stream>>>(hb, lng, lnb, Ws, bs, spanb);
  bump_kernel<<<dim3(ROWS / 256), 256, 0, stream>>>(spanb, eb, out);
}

// Round 5
// 201.240 us; speedup vs baseline: 1.2846x; 1.0887x over previous
//
#include <hip/hip_runtime.h>
#include <math.h>

#define SEQ 512
#define HID 768
#define NBATCH 16
#define ROWS 8192
#define INV_SQRT_D 0.07216878364870323f

typedef short s8v __attribute__((ext_vector_type(8)));
typedef _Float16 h8v __attribute__((ext_vector_type(8)));
typedef float f4v __attribute__((ext_vector_type(4)));
typedef unsigned short u16;

// ---- fp16 helper (RNE) ----
__device__ __forceinline__ u16 f2h(float f) {
  _Float16 h = (_Float16)f;
  return __builtin_bit_cast(u16, h);
}

// ---- async global->LDS 16B copy (m97/m151: 1.35x over reg-staging) ----
// LDS dest must be wave-uniform base (HW adds lane*16); global src is per-lane.
__device__ __forceinline__ void llds16(const u16* g, u16* l) {
  __builtin_amdgcn_global_load_lds(
      (const __attribute__((address_space(1))) void*)g,
      (__attribute__((address_space(3))) void*)l, 16, 0, 0);
}

// ---------------------------------------------------------------------------
// fp16 GEMM core (R13): BK=64 via paired 32-wide sub-tiles, staged with
// global_load_lds (direct-to-LDS DMA). Source address carries the csw
// pre-swizzle (m173 pattern: pre-swizzled global + linear-in-lane LDS dest);
// fragment reads keep the fo2 swizzle (conflict-free b128).
// LDS 32KB: sub0 {A@0,B@4096}, sub1 {A@8192,B@12288} (u16 idx).
// ---------------------------------------------------------------------------
template <int KSTEPS>   // number of 32-wide steps; must be even
__device__ __forceinline__ void mm_core128(
    const u16* __restrict__ A, const int lda,
    const u16* __restrict__ B, const int ldb,
    u16* lds, f4v (&acc)[4][4])
{
  const int tid = threadIdx.x;
  const int w = tid >> 6, ln = tid & 63;
  const u16* src = (w >> 1) ? B : A;
  const int ld = (w >> 1) ? ldb : lda;
  const int half = w & 1;
  const int srow = ln >> 2;
  const int csw  = ((ln & 3) - (ln >> 3)) & 3;
  const int ml = ln & 15;
  const int fo2 = (((ln >> 4) + ((ln >> 1) & 3)) & 3) * 8;
  const int wr = (w >> 1) * 64, wc = (w & 1) * 64;

  const u16* gp[4];
  u16* lp[4];
#pragma unroll
  for (int t = 0; t < 4; ++t) {
    const int row = half * 64 + t * 16 + srow;
    gp[t] = src + (size_t)row * ld + csw * 8;
    lp[t] = lds + (w >> 1) * 4096 + half * 2048 + t * 512;   // wave-uniform
  }

  for (int kp = 0; kp < KSTEPS / 2; ++kp) {
    const int k0 = kp * 64;
    __syncthreads();                       // prev-iter LDS reads done
#pragma unroll
    for (int t = 0; t < 4; ++t) {
      llds16(gp[t] + k0,      lp[t]);
      llds16(gp[t] + k0 + 32, lp[t] + 8192);
    }
    __syncthreads();                       // vmcnt(0) drain + visibility
#pragma unroll
    for (int sub = 0; sub < 2; ++sub) {
      const int so = sub * 8192;
      h8v a[4], b[4];
#pragma unroll
      for (int i = 0; i < 4; ++i)
        a[i] = *(const h8v*)&lds[so + (wr + i * 16 + ml) * 32 + fo2];
#pragma unroll
      for (int j = 0; j < 4; ++j)
        b[j] = *(const h8v*)&lds[so + 4096 + (wc + j * 16 + ml) * 32 + fo2];
#pragma unroll
      for (int i = 0; i < 4; ++i)
#pragma unroll
        for (int j = 0; j < 4; ++j)
          acc[i][j] = __builtin_amdgcn_mfma_f32_16x16x32_f16(a[i], b[j], acc[i][j], 0, 0, 0);
    }
  }
}

// ---- prep: x -> fp16 ----
__global__ __launch_bounds__(256) void splitx(const float* __restrict__ x,
                                              u16* __restrict__ xh)
{
  const int i = blockIdx.x * 256 + threadIdx.x;
  const float4 v = ((const float4*)x)[i];
  ((ushort4*)xh)[i] = make_ushort4(f2h(v.x), f2h(v.y), f2h(v.z), f2h(v.w));
}

// ---- prep: transpose weights: WT[z][n][k] = W_z[k][n], fp16 ----
__global__ __launch_bounds__(256) void wsplit(
    const float* __restrict__ Wq, const float* __restrict__ Wk,
    const float* __restrict__ Wv, const float* __restrict__ Wo,
    u16* __restrict__ WTh)
{
  __shared__ float t[32][33];
  const int z = blockIdx.z;
  const float* W = (z == 0) ? Wq : (z == 1) ? Wk : (z == 2) ? Wv : Wo;
  const int n0 = blockIdx.x * 32, k0 = blockIdx.y * 32;
  const int tx = threadIdx.x & 31, ty = threadIdx.x >> 5;
#pragma unroll
  for (int i = 0; i < 4; ++i)
    t[ty + 8 * i][tx] = W[(size_t)(k0 + ty + 8 * i) * HID + n0 + tx];
  __syncthreads();
#pragma unroll
  for (int i = 0; i < 4; ++i) {
    const float v = t[tx][ty + 8 * i];
    const size_t idx = (size_t)z * HID * HID + (size_t)(n0 + ty + 8 * i) * HID + k0 + tx;
    WTh[idx] = f2h(v);
  }
}

// ---- QKV GEMM, XCD-swizzled 1D grid (1152 blocks), gll fp16 BK=64 core.
//      All epilogues go through LDS for coalesced 16B stores:
//      z<2 (q,k): row-major tile, stride 132 (quad rows -> bank offs 0/8/16/24,
//      conflict-free); z==2 (v): transposed tile, stride 136 (R14). ----
__global__ __launch_bounds__(256, 4) void qkv_mm(
    const u16* __restrict__ xh, const u16* __restrict__ WTh,
    const float* __restrict__ bq, const float* __restrict__ bk, const float* __restrict__ bv,
    u16* __restrict__ qh, u16* __restrict__ kh, u16* __restrict__ vTh)
{
  __shared__ u16 lds[18432];        // mm_core: 16384; epilogue: 128x144 max
  const int id = blockIdx.x;
  const int xcd = id & 7;
  const int s = id >> 3;            // 0..143
  const int bx = s % 6;
  const int yl = (s / 6) & 7;
  const int z  = s / 48;
  const int bm = (yl * 8 + xcd) * 128;
  const int bn = bx * 128;
  const size_t wtoff = (size_t)z * HID * HID + (size_t)bn * HID;
  f4v acc[4][4];
#pragma unroll
  for (int i = 0; i < 4; ++i)
#pragma unroll
    for (int j = 0; j < 4; ++j) acc[i][j] = (f4v)0.f;
  mm_core128<24>(xh + (size_t)bm * HID, HID, WTh + wtoff, HID, lds, acc);
  const int tid = threadIdx.x, w = tid >> 6, ln = tid & 63;
  const int ml = ln & 15, quad = ln >> 4;
  const int wr = (w >> 1) * 64, wc = (w & 1) * 64;
  if (z == 2) {
    // transpose via LDS: lds[n_local*136 + seq_local], then coalesced out
    __syncthreads();                       // mm_core's last LDS reads done
#pragma unroll
    for (int i = 0; i < 4; ++i)
#pragma unroll
      for (int j = 0; j < 4; ++j) {
        const int ncol = wc + j * 16 + ml;
        const float bv_ = bv[bn + ncol];
#pragma unroll
        for (int r = 0; r < 4; ++r) {
          const int srow = wr + i * 16 + quad * 4 + r;
          lds[ncol * 136 + srow] = f2h(acc[i][j][r] + bv_);
        }
      }
    __syncthreads();
    u16* vb = vTh + (size_t)(bm >> 9) * HID * SEQ;
    const int sq0 = bm & 511;
    const int c8 = (tid & 15) * 8;
#pragma unroll
    for (int p = 0; p < 8; ++p) {
      const int nl = p * 16 + (tid >> 4);  // 0..127
      const s8v val = *(const s8v*)&lds[nl * 136 + c8];
      *(s8v*)&vb[(size_t)(bn + nl) * SEQ + sq0 + c8] = val;
    }
  } else {
    // q/k: row-major LDS tile (stride 132), then 16B coalesced row stores
    const float* bias = (z == 0) ? bq : bk;
    u16* dst = (z == 0) ? qh : kh;
    __syncthreads();                       // mm_core's last LDS reads done
#pragma unroll
    for (int i = 0; i < 4; ++i)
#pragma unroll
      for (int j = 0; j < 4; ++j) {
        const int col = wc + j * 16 + ml;
        const float bv_ = bias[bn + col];
#pragma unroll
        for (int r = 0; r < 4; ++r) {
          const int row = wr + i * 16 + quad * 4 + r;
          lds[row * 132 + col] = f2h(acc[i][j][r] + bv_);
        }
      }
    __syncthreads();
    const int c8 = (tid & 15) * 8;
#pragma unroll
    for (int p = 0; p < 8; ++p) {
      const int rl = p * 16 + (tid >> 4);  // 0..127
      const s8v val = *(const s8v*)&lds[rl * 132 + c8];
      *(s8v*)&dst[(size_t)(bm + rl) * HID + bn + c8] = val;
    }
  }
}

// ---------------------------------------------------------------------------
// FLASH attention v4 (R14): 64 Q-rows per block -> 512 blocks = exactly
// 2 blocks/CU x 256 CU, ONE resident round, zero tail. Per K-block j of 64:
// stage K_j[64][200] + vT_j[192][72] (padded strides: conflict-free b128),
// reg-prefetch j+1 under MFMA+softmax; QK^T 24 MFMA/wave -> max-free exp via
// g-table (exact; validated R11-R13) -> P[64][72] -> PV 24 MFMA/wave.
// 3 barriers/iter; one sum-reduce at end; setprio around MFMA (T5).
// Grid XCD-bijective: 8 (b,h)/XCD -> K+V 3.1MB < 4MB L2. LDS 62.5KB+gtab.
// ---------------------------------------------------------------------------
__global__ __launch_bounds__(256, 2) void attn_fused(
    const u16* __restrict__ qh, const u16* __restrict__ kh,
    const u16* __restrict__ vTh, u16* __restrict__ ch)
{
  __shared__ u16 lds[31232];
  __shared__ float gtab[1024];
  __shared__ float red[4][32];
  const int f = blockIdx.x;            // 512 blocks
  const int xcd = f & 7, s = f >> 3;   // s: 0..63
  const int z = xcd * 8 + (s >> 3);    // (b,h) 0..63, 8 per XCD
  const int bm = (s & 7) * 64;
  const int b = z >> 2, hh = z & 3;
  const int tid = threadIdx.x, w = tid >> 6, ln = tid & 63;
  const int ml = ln & 15, quad = ln >> 4;
  const int rh = w >> 1, ch2 = w & 1;  // row-half / col-half of the wave

  // g-table: idx = (srow - scol) + 511
  for (int t = tid; t < 1023; t += 256) {
    const float fd = fabsf((float)(t - 511));
    gtab[t] = INV_SQRT_D * __expf(-0.1f * fminf(fd, 5.0f)) - 0.1f * fd;
  }

  const u16* qbase = qh + (size_t)(b * SEQ + bm + rh * 32) * HID + hh * 192;
  const u16* kbase = kh + (size_t)b * SEQ * HID + hh * 192;
  const u16* vbase = vTh + (size_t)b * HID * SEQ + (size_t)(hh * 192) * SEQ;

  // Q fragments in registers (wave's 32 rows)
  h8v qf[2][6];
#pragma unroll
  for (int i = 0; i < 2; ++i)
#pragma unroll
    for (int ks = 0; ks < 6; ++ks)
      qf[i][ks] = *(const h8v*)(qbase + (size_t)(i * 16 + ml) * HID + ks * 32 + quad * 8);

  // staging decomposition: 1536 8-u16 chunks each for K_j and vT_j
  int koff[6], kldso[6], voff[6], vldso[6];
#pragma unroll
  for (int c = 0; c < 6; ++c) {
    const int cc = c * 256 + tid;
    const int krow = cc / 24, kcol = cc % 24;      // K_j: [64 rows][24 chunks]
    koff[c]  = krow * HID + kcol * 8;
    kldso[c] = krow * 200 + kcol * 8;
    const int vrow = cc >> 3, vcol = cc & 7;       // vT_j: [192 rows][8 chunks]
    voff[c]  = vrow * SEQ + vcol * 8;
    vldso[c] = 12800 + vrow * 72 + vcol * 8;
  }
  s8v kc[6], vc[6];
#pragma unroll
  for (int c = 0; c < 6; ++c) {
    kc[c] = *(const s8v*)(kbase + koff[c]);
    vc[c] = *(const s8v*)(vbase + voff[c]);
  }

  f4v acc2[2][6];
#pragma unroll
  for (int i = 0; i < 2; ++i)
#pragma unroll
    for (int jj = 0; jj < 6; ++jj) acc2[i][jj] = (f4v)0.f;
  float rsum[2][4];
#pragma unroll
  for (int i = 0; i < 2; ++i)
#pragma unroll
    for (int r = 0; r < 4; ++r) rsum[i][r] = 0.f;

  for (int j = 0; j < 8; ++j) {
    __syncthreads();                       // b1: prev-iter LDS reads done
#pragma unroll
    for (int c = 0; c < 6; ++c) {
      *(s8v*)&lds[kldso[c]] = kc[c];
      *(s8v*)&lds[vldso[c]] = vc[c];
    }
    __syncthreads();                       // b2: K_j/vT_j (+gtab, j==0) visible
    if (j < 7) {                           // prefetch next K-block into regs
      const int ko = (j + 1) * 64;
#pragma unroll
      for (int c = 0; c < 6; ++c) {
        kc[c] = *(const s8v*)(kbase + (size_t)ko * HID + koff[c]);
        vc[c] = *(const s8v*)(vbase + ko + voff[c]);
      }
    }
    // ---- QK^T: 24 MFMA/wave (64Q x 32K per wave) ----
    f4v sacc[2][2];
    sacc[0][0] = (f4v)0.f; sacc[0][1] = (f4v)0.f;
    sacc[1][0] = (f4v)0.f; sacc[1][1] = (f4v)0.f;
    __builtin_amdgcn_s_setprio(1);
#pragma unroll
    for (int ks = 0; ks < 6; ++ks) {
      h8v kf0 = *(const h8v*)&lds[(ch2 * 32 + ml) * 200 + ks * 32 + quad * 8];
      h8v kf1 = *(const h8v*)&lds[(ch2 * 32 + 16 + ml) * 200 + ks * 32 + quad * 8];
      sacc[0][0] = __builtin_amdgcn_mfma_f32_16x16x32_f16(qf[0][ks], kf0, sacc[0][0], 0, 0, 0);
      sacc[1][0] = __builtin_amdgcn_mfma_f32_16x16x32_f16(qf[1][ks], kf0, sacc[1][0], 0, 0, 0);
      sacc[0][1] = __builtin_amdgcn_mfma_f32_16x16x32_f16(qf[0][ks], kf1, sacc[0][1], 0, 0, 0);
      sacc[1][1] = __builtin_amdgcn_mfma_f32_16x16x32_f16(qf[1][ks], kf1, sacc[1][1], 0, 0, 0);
    }
    __builtin_amdgcn_s_setprio(0);
    // ---- transform + P write (max-free exp; 1 exp/elem via g-table) ----
#pragma unroll
    for (int i = 0; i < 2; ++i)
#pragma unroll
      for (int j2 = 0; j2 < 2; ++j2) {
        const int lcol = ch2 * 32 + j2 * 16 + ml;
        const int scolg = j * 64 + lcol;
#pragma unroll
        for (int r = 0; r < 4; ++r) {
          const int lrow = rh * 32 + i * 16 + quad * 4 + r;
          const float g = gtab[bm + lrow - scolg + 511];
          const float p = __expf(fmaf(sacc[i][j2][r], INV_SQRT_D, g));
          rsum[i][r] += p;
          lds[26624 + lrow * 72 + lcol] = f2h(p);
        }
      }
    __syncthreads();                       // b3: P_j visible
    // ---- PV: 24 MFMA/wave (64Q x 96 head-dims per wave) ----
    __builtin_amdgcn_s_setprio(1);
#pragma unroll
    for (int ks = 0; ks < 2; ++ks) {
      h8v pf[2], vf[6];
#pragma unroll
      for (int i = 0; i < 2; ++i)
        pf[i] = *(const h8v*)&lds[26624 + (rh * 32 + i * 16 + ml) * 72 + ks * 32 + quad * 8];
#pragma unroll
      for (int jj = 0; jj < 6; ++jj)
        vf[jj] = *(const h8v*)&lds[12800 + (ch2 * 96 + jj * 16 + ml) * 72 + ks * 32 + quad * 8];
#pragma unroll
      for (int i = 0; i < 2; ++i)
#pragma unroll
        for (int jj = 0; jj < 6; ++jj)
          acc2[i][jj] = __builtin_amdgcn_mfma_f32_16x16x32_f16(pf[i], vf[jj], acc2[i][jj], 0, 0, 0);
    }
    __builtin_amdgcn_s_setprio(0);
  }

  // ---- final row-sum reduce ----
#pragma unroll
  for (int i = 0; i < 2; ++i)
#pragma unroll
    for (int r = 0; r < 4; ++r) {
      float t = rsum[i][r];
#pragma unroll
      for (int o = 1; o < 16; o <<= 1) t += __shfl_xor(t, o, 64);
      rsum[i][r] = t;
    }
  if (ml == 0) {
#pragma unroll
    for (int i = 0; i < 2; ++i)
#pragma unroll
      for (int r = 0; r < 4; ++r) red[w][i * 16 + quad * 4 + r] = rsum[i][r];
  }
  __syncthreads();

  // ---- ctx out (normalize here) ----
#pragma unroll
  for (int i = 0; i < 2; ++i)
#pragma unroll
    for (int r = 0; r < 4; ++r) {
      const int lr = i * 16 + quad * 4 + r;
      const float is = 1.0f / (red[rh * 2][lr] + red[rh * 2 + 1][lr]);
      const int m = bm + rh * 32 + lr;
#pragma unroll
      for (int jj = 0; jj < 6; ++jj) {
        const int gcol = hh * 192 + ch2 * 96 + jj * 16 + ml;
        ch[(size_t)(b * SEQ + m) * HID + gcol] = f2h(acc2[i][jj][r] * is);
      }
    }
}

// ---- projection GEMM + bias + residual -> h fp32 (XCD-swizzled, gll fp16) ----
__global__ __launch_bounds__(256, 4) void proj_mm(
    const u16* __restrict__ ch, const u16* __restrict__ WTh,
    const float* __restrict__ bo, const float* __restrict__ x, float* __restrict__ h)
{
  __shared__ u16 lds[16384];
  const int id = blockIdx.x;
  const int xcd = id & 7;
  const int s = id >> 3;            // 0..47
  const int bx = s % 6;
  const int yl = s / 6;             // 0..7
  const int bm = (yl * 8 + xcd) * 128;
  const int bn = bx * 128;
  const size_t wtoff = (size_t)3 * HID * HID + (size_t)bn * HID;
  f4v acc[4][4];
#pragma unroll
  for (int i = 0; i < 4; ++i)
#pragma unroll
    for (int j = 0; j < 4; ++j) acc[i][j] = (f4v)0.f;
  mm_core128<24>(ch + (size_t)bm * HID, HID, WTh + wtoff, HID, lds, acc);
  const int tid = threadIdx.x, w = tid >> 6, ln = tid & 63;
  const int ml = ln & 15, quad = ln >> 4;
  const int wr = (w >> 1) * 64, wc = (w & 1) * 64;
#pragma unroll
  for (int i = 0; i < 4; ++i)
#pragma unroll
    for (int j = 0; j < 4; ++j) {
      const int gcol = bn + wc + j * 16 + ml;
      const float bv_ = bo[gcol];
#pragma unroll
      for (int r = 0; r < 4; ++r) {
        const int grow = bm + wr + i * 16 + quad * 4 + r;
        const size_t idx = (size_t)grow * HID + gcol;
        h[idx] = acc[i][j][r] + bv_ + x[idx];
      }
    }
}

// ---- LayerNorm + 9-label classifier: ONE WAVE per row (R15).
//      shfl_xor-only reductions -> zero barriers, zero LDS. 4 rows/block. ----
__global__ __launch_bounds__(256) void ln_logits_kernel(
    const float* __restrict__ h, const float* __restrict__ g,
    const float* __restrict__ bta, const float* __restrict__ Ws,
    const float* __restrict__ bsv, float* __restrict__ span)
{
  const int row = blockIdx.x * 4 + (threadIdx.x >> 6);
  const int lane = threadIdx.x & 63;
  const float* hr = h + (size_t)row * HID;
  float4 v[3];
#pragma unroll
  for (int sgm = 0; sgm < 3; ++sgm) v[sgm] = ((const float4*)hr)[sgm * 64 + lane];
  float s = 0.f, sq = 0.f;
#pragma unroll
  for (int sgm = 0; sgm < 3; ++sgm) {
    s  += v[sgm].x + v[sgm].y + v[sgm].z + v[sgm].w;
    sq += v[sgm].x * v[sgm].x + v[sgm].y * v[sgm].y
        + v[sgm].z * v[sgm].z + v[sgm].w * v[sgm].w;
  }
#pragma unroll
  for (int o = 1; o < 64; o <<= 1) { s += __shfl_xor(s, o, 64); sq += __shfl_xor(sq, o, 64); }
  const float mu = s / 768.0f;
  const float rs = rsqrtf(sq / 768.0f - mu * mu + 1e-5f);
  float pl[9];
#pragma unroll
  for (int l = 0; l < 9; ++l) pl[l] = 0.f;
#pragma unroll
  for (int sgm = 0; sgm < 3; ++sgm) {
    const int c0 = sgm * 256 + lane * 4;
    const float4 gg = ((const float4*)g)[sgm * 64 + lane];
    const float4 bb = ((const float4*)bta)[sgm * 64 + lane];
    const float n0 = (v[sgm].x - mu) * rs * gg.x + bb.x;
    const float n1 = (v[sgm].y - mu) * rs * gg.y + bb.y;
    const float n2 = (v[sgm].z - mu) * rs * gg.z + bb.z;
    const float n3 = (v[sgm].w - mu) * rs * gg.w + bb.w;
    const float* w0 = Ws + (size_t)c0 * 9;
#pragma unroll
    for (int l = 0; l < 9; ++l)
      pl[l] += n0 * w0[l] + n1 * w0[9 + l] + n2 * w0[18 + l] + n3 * w0[27 + l];
  }
#pragma unroll
  for (int l = 0; l < 9; ++l)
#pragma unroll
    for (int o = 1; o < 64; o <<= 1) pl[l] += __shfl_xor(pl[l], o, 64);
  if (lane == 0) {
    float* sp = span + (size_t)row * 9;
#pragma unroll
    for (int l = 0; l < 9; ++l) sp[l] = pl[l] + bsv[l];
  }
}

// ---- entity-bias bump ----
__global__ __launch_bounds__(256) void bump_kernel(
    const float* __restrict__ span, const float* __restrict__ eb, float* __restrict__ out)
{
  const int idx = blockIdx.x * 256 + threadIdx.x;
  if (idx >= ROWS) return;
  const int j = idx & (SEQ - 1);
  const float* sl = span + (size_t)idx * 9;
  float v[9];
#pragma unroll
  for (int l = 0; l < 9; ++l) v[l] = sl[l];
  if (j >= 1) {
    const float* sp = sl - 9;
    float m = sp[0]; int am = 0;
#pragma unroll
    for (int l = 1; l < 9; ++l) { const float t = sp[l]; if (t > m) { m = t; am = l; } }
    if (am == 1) v[2] += 2.0f * eb[2];
  }
#pragma unroll
  for (int l = 0; l < 9; ++l) out[(size_t)idx * 9 + l] = v[l];
}

extern "C" void kernel_launch(void* const* d_in, const int* in_sizes, int n_in,
                              void* d_out, int out_size, void* d_ws, size_t ws_size,
                              hipStream_t stream)
{
  (void)in_sizes; (void)n_in; (void)out_size; (void)ws_size;
  const float* x   = (const float*)d_in[0];
  const float* Wq  = (const float*)d_in[1];
  const float* bq  = (const float*)d_in[2];
  const float* Wk  = (const float*)d_in[3];
  const float* bk  = (const float*)d_in[4];
  const float* Wv  = (const float*)d_in[5];
  const float* bv  = (const float*)d_in[6];
  const float* Wo  = (const float*)d_in[7];
  const float* bo  = (const float*)d_in[8];
  const float* lng = (const float*)d_in[9];
  const float* lnb = (const float*)d_in[10];
  const float* Ws  = (const float*)d_in[11];
  const float* bs  = (const float*)d_in[12];
  const float* eb  = (const float*)d_in[13];
  float* out = (float*)d_out;

  char* ws = (char*)d_ws;
  u16* xh  = (u16*)(ws + 0);                       // fp16 x (12.6MB)
  u16* WTh = (u16*)(ws + 25165824);                // fp16 WT (4 matrices)
  u16* qh  = (u16*)(ws + 34603008);
  u16* kh  = (u16*)(ws + 59768832);
  u16* vTh = (u16*)(ws + 84934656);                // fp16 vT (12.6MB)
  float* hb = (float*)(ws + 84934656);             // fp32 h (25MB, overwrites vT after attn)
  float* spanb = (float*)(ws + 152043520);
  u16* ctxh = qh;                                  // q dead after attn

  splitx<<<dim3(1572864 / 256), 256, 0, stream>>>(x, xh);
  wsplit<<<dim3(24, 24, 4), 256, 0, stream>>>(Wq, Wk, Wv, Wo, WTh);
  qkv_mm<<<dim3(1152), 256, 0, stream>>>(xh, WTh, bq, bk, bv, qh, kh, vTh);
  attn_fused<<<dim3(512), 256, 0, stream>>>(qh, kh, vTh, ctxh);
  proj_mm<<<dim3(384), 256, 0, stream>>>(ctxh, WTh, bo, x, hb);
  ln_logits_kernel<<<dim3(ROWS / 4), 256, 0, stream>>>(hb, lng, lnb, Ws, bs, spanb);
  bump_kernel<<<dim3(ROWS / 256), 256, 0, stream>>>(spanb, eb, out);
}

// Round 6
// 199.062 us; speedup vs baseline: 1.2987x; 1.0109x over previous
//
#include <hip/hip_runtime.h>
#include <math.h>

#define SEQ 512
#define HID 768
#define NBATCH 16
#define ROWS 8192
#define INV_SQRT_D 0.07216878364870323f

typedef short s8v __attribute__((ext_vector_type(8)));
typedef _Float16 h8v __attribute__((ext_vector_type(8)));
typedef float f4v __attribute__((ext_vector_type(4)));
typedef unsigned short u16;

// ---- fp16 helper (RNE) ----
__device__ __forceinline__ u16 f2h(float f) {
  _Float16 h = (_Float16)f;
  return __builtin_bit_cast(u16, h);
}

// ---- async global->LDS 16B copy (m97/m151: 1.35x over reg-staging) ----
// LDS dest must be wave-uniform base (HW adds lane*16); global src is per-lane.
__device__ __forceinline__ void llds16(const u16* g, u16* l) {
  __builtin_amdgcn_global_load_lds(
      (const __attribute__((address_space(1))) void*)g,
      (__attribute__((address_space(3))) void*)l, 16, 0, 0);
}

// ---------------------------------------------------------------------------
// fp16 GEMM core (R13): BK=64 via paired 32-wide sub-tiles, staged with
// global_load_lds (direct-to-LDS DMA). Source address carries the csw
// pre-swizzle (m173 pattern: pre-swizzled global + linear-in-lane LDS dest);
// fragment reads keep the fo2 swizzle (conflict-free b128).
// LDS 32KB: sub0 {A@0,B@4096}, sub1 {A@8192,B@12288} (u16 idx).
// ---------------------------------------------------------------------------
template <int KSTEPS>   // number of 32-wide steps; must be even
__device__ __forceinline__ void mm_core128(
    const u16* __restrict__ A, const int lda,
    const u16* __restrict__ B, const int ldb,
    u16* lds, f4v (&acc)[4][4])
{
  const int tid = threadIdx.x;
  const int w = tid >> 6, ln = tid & 63;
  const u16* src = (w >> 1) ? B : A;
  const int ld = (w >> 1) ? ldb : lda;
  const int half = w & 1;
  const int srow = ln >> 2;
  const int csw  = ((ln & 3) - (ln >> 3)) & 3;
  const int ml = ln & 15;
  const int fo2 = (((ln >> 4) + ((ln >> 1) & 3)) & 3) * 8;
  const int wr = (w >> 1) * 64, wc = (w & 1) * 64;

  const u16* gp[4];
  u16* lp[4];
#pragma unroll
  for (int t = 0; t < 4; ++t) {
    const int row = half * 64 + t * 16 + srow;
    gp[t] = src + (size_t)row * ld + csw * 8;
    lp[t] = lds + (w >> 1) * 4096 + half * 2048 + t * 512;   // wave-uniform
  }

  for (int kp = 0; kp < KSTEPS / 2; ++kp) {
    const int k0 = kp * 64;
    __syncthreads();                       // prev-iter LDS reads done
#pragma unroll
    for (int t = 0; t < 4; ++t) {
      llds16(gp[t] + k0,      lp[t]);
      llds16(gp[t] + k0 + 32, lp[t] + 8192);
    }
    __syncthreads();                       // vmcnt(0) drain + visibility
#pragma unroll
    for (int sub = 0; sub < 2; ++sub) {
      const int so = sub * 8192;
      h8v a[4], b[4];
#pragma unroll
      for (int i = 0; i < 4; ++i)
        a[i] = *(const h8v*)&lds[so + (wr + i * 16 + ml) * 32 + fo2];
#pragma unroll
      for (int j = 0; j < 4; ++j)
        b[j] = *(const h8v*)&lds[so + 4096 + (wc + j * 16 + ml) * 32 + fo2];
#pragma unroll
      for (int i = 0; i < 4; ++i)
#pragma unroll
        for (int j = 0; j < 4; ++j)
          acc[i][j] = __builtin_amdgcn_mfma_f32_16x16x32_f16(a[i], b[j], acc[i][j], 0, 0, 0);
    }
  }
}

// ---- prep: x -> fp16 ----
__global__ __launch_bounds__(256) void splitx(const float* __restrict__ x,
                                              u16* __restrict__ xh)
{
  const int i = blockIdx.x * 256 + threadIdx.x;
  const float4 v = ((const float4*)x)[i];
  ((ushort4*)xh)[i] = make_ushort4(f2h(v.x), f2h(v.y), f2h(v.z), f2h(v.w));
}

// ---- prep: transpose weights: WT[z][n][k] = W_z[k][n], fp16 ----
__global__ __launch_bounds__(256) void wsplit(
    const float* __restrict__ Wq, const float* __restrict__ Wk,
    const float* __restrict__ Wv, const float* __restrict__ Wo,
    u16* __restrict__ WTh)
{
  __shared__ float t[32][33];
  const int z = blockIdx.z;
  const float* W = (z == 0) ? Wq : (z == 1) ? Wk : (z == 2) ? Wv : Wo;
  const int n0 = blockIdx.x * 32, k0 = blockIdx.y * 32;
  const int tx = threadIdx.x & 31, ty = threadIdx.x >> 5;
#pragma unroll
  for (int i = 0; i < 4; ++i)
    t[ty + 8 * i][tx] = W[(size_t)(k0 + ty + 8 * i) * HID + n0 + tx];
  __syncthreads();
#pragma unroll
  for (int i = 0; i < 4; ++i) {
    const float v = t[tx][ty + 8 * i];
    const size_t idx = (size_t)z * HID * HID + (size_t)(n0 + ty + 8 * i) * HID + k0 + tx;
    WTh[idx] = f2h(v);
  }
}

// ---- QKV GEMM, XCD-swizzled 1D grid (1152 blocks), gll fp16 BK=64 core.
//      All epilogues go through LDS for coalesced 16B stores:
//      z<2 (q,k): row-major tile, stride 132 (quad rows -> bank offs 0/8/16/24,
//      conflict-free); z==2 (v): transposed tile, stride 136 (R14). ----
__global__ __launch_bounds__(256, 4) void qkv_mm(
    const u16* __restrict__ xh, const u16* __restrict__ WTh,
    const float* __restrict__ bq, const float* __restrict__ bk, const float* __restrict__ bv,
    u16* __restrict__ qh, u16* __restrict__ kh, u16* __restrict__ vTh)
{
  __shared__ u16 lds[18432];        // mm_core: 16384; epilogue: 128x144 max
  const int id = blockIdx.x;
  const int xcd = id & 7;
  const int s = id >> 3;            // 0..143
  const int bx = s % 6;
  const int yl = (s / 6) & 7;
  const int z  = s / 48;
  const int bm = (yl * 8 + xcd) * 128;
  const int bn = bx * 128;
  const size_t wtoff = (size_t)z * HID * HID + (size_t)bn * HID;
  f4v acc[4][4];
#pragma unroll
  for (int i = 0; i < 4; ++i)
#pragma unroll
    for (int j = 0; j < 4; ++j) acc[i][j] = (f4v)0.f;
  mm_core128<24>(xh + (size_t)bm * HID, HID, WTh + wtoff, HID, lds, acc);
  const int tid = threadIdx.x, w = tid >> 6, ln = tid & 63;
  const int ml = ln & 15, quad = ln >> 4;
  const int wr = (w >> 1) * 64, wc = (w & 1) * 64;
  if (z == 2) {
    // transpose via LDS: lds[n_local*136 + seq_local], then coalesced out
    __syncthreads();                       // mm_core's last LDS reads done
#pragma unroll
    for (int i = 0; i < 4; ++i)
#pragma unroll
      for (int j = 0; j < 4; ++j) {
        const int ncol = wc + j * 16 + ml;
        const float bv_ = bv[bn + ncol];
#pragma unroll
        for (int r = 0; r < 4; ++r) {
          const int srow = wr + i * 16 + quad * 4 + r;
          lds[ncol * 136 + srow] = f2h(acc[i][j][r] + bv_);
        }
      }
    __syncthreads();
    u16* vb = vTh + (size_t)(bm >> 9) * HID * SEQ;
    const int sq0 = bm & 511;
    const int c8 = (tid & 15) * 8;
#pragma unroll
    for (int p = 0; p < 8; ++p) {
      const int nl = p * 16 + (tid >> 4);  // 0..127
      const s8v val = *(const s8v*)&lds[nl * 136 + c8];
      *(s8v*)&vb[(size_t)(bn + nl) * SEQ + sq0 + c8] = val;
    }
  } else {
    // q/k: row-major LDS tile (stride 132), then 16B coalesced row stores
    const float* bias = (z == 0) ? bq : bk;
    u16* dst = (z == 0) ? qh : kh;
    __syncthreads();                       // mm_core's last LDS reads done
#pragma unroll
    for (int i = 0; i < 4; ++i)
#pragma unroll
      for (int j = 0; j < 4; ++j) {
        const int col = wc + j * 16 + ml;
        const float bv_ = bias[bn + col];
#pragma unroll
        for (int r = 0; r < 4; ++r) {
          const int row = wr + i * 16 + quad * 4 + r;
          lds[row * 132 + col] = f2h(acc[i][j][r] + bv_);
        }
      }
    __syncthreads();
    const int c8 = (tid & 15) * 8;
#pragma unroll
    for (int p = 0; p < 8; ++p) {
      const int rl = p * 16 + (tid >> 4);  // 0..127
      const s8v val = *(const s8v*)&lds[rl * 132 + c8];
      *(s8v*)&dst[(size_t)(bm + rl) * HID + bn + c8] = val;
    }
  }
}

// ---------------------------------------------------------------------------
// FLASH attention v5 (R16): 64 Q-rows/block, 512 blocks = 2 blocks/CU, one
// resident round. K/V staging now via global_load_lds DIRECT (m97 schedule):
// K = 6 sub-tiles [64][32], V = 2 sub-tiles [192][32], each with the mm_core
// csw/fo2 swizzle carried on the per-lane GLOBAL source address (m173), LDS
// dest linear-in-lane -> 12 llds16/wave/iter replace 12 global b128 loads +
// 12 ds_write_b128 and free ~48 staging VGPRs. L2 latency between b1/b2 is
// hidden by the co-resident block (m114). QK^T 24 MFMA/wave -> max-free exp
// via g-table (exact; validated R11+) -> P[64][72] -> PV 24 MFMA/wave.
// Grid XCD-bijective: 8 (b,h)/XCD -> K+V 3.1MB < 4MB L2.
// LDS: K@0 (12288), V@12288 (12288), P@24576 (4608) u16 = 57KB +gtab+red.
// ---------------------------------------------------------------------------
__global__ __launch_bounds__(256, 2) void attn_fused(
    const u16* __restrict__ qh, const u16* __restrict__ kh,
    const u16* __restrict__ vTh, u16* __restrict__ ch)
{
  __shared__ u16 lds[29184];
  __shared__ float gtab[1024];
  __shared__ float red[4][32];
  const int f = blockIdx.x;            // 512 blocks
  const int xcd = f & 7, s = f >> 3;   // s: 0..63
  const int z = xcd * 8 + (s >> 3);    // (b,h) 0..63, 8 per XCD
  const int bm = (s & 7) * 64;
  const int b = z >> 2, hh = z & 3;
  const int tid = threadIdx.x, w = tid >> 6, ln = tid & 63;
  const int ml = ln & 15, quad = ln >> 4;
  const int rh = w >> 1, ch2 = w & 1;  // row-half / col-half of the wave
  const int fo2 = ((quad + ((ml >> 1) & 3)) & 3) * 8;

  // g-table: idx = (srow - scol) + 511
  for (int t = tid; t < 1023; t += 256) {
    const float fd = fabsf((float)(t - 511));
    gtab[t] = INV_SQRT_D * __expf(-0.1f * fminf(fd, 5.0f)) - 0.1f * fd;
  }

  const u16* qbase = qh + (size_t)(b * SEQ + bm + rh * 32) * HID + hh * 192;
  const u16* kbase = kh + (size_t)b * SEQ * HID + hh * 192;
  const u16* vbase = vTh + (size_t)b * HID * SEQ + (size_t)(hh * 192) * SEQ;

  // Q fragments in registers (wave's 32 rows)
  h8v qf[2][6];
#pragma unroll
  for (int i = 0; i < 2; ++i)
#pragma unroll
    for (int ks = 0; ks < 6; ++ks)
      qf[i][ks] = *(const h8v*)(qbase + (size_t)(i * 16 + ml) * HID + ks * 32 + quad * 8);

  // gll staging geometry: lane ln covers row (ln>>2), slot (ln&3); the
  // conflict-free swizzle is applied on the SOURCE chunk index (csw).
  const int srow16 = ln >> 2;
  const int csw = ((ln & 3) - (ln >> 3)) & 3;
  const u16* ksrc = kbase + (size_t)(w * 16 + srow16) * HID + csw * 8;
  const u16* vsrc = vbase + (size_t)(w * 48 + srow16) * SEQ + csw * 8;

  f4v acc2[2][6];
#pragma unroll
  for (int i = 0; i < 2; ++i)
#pragma unroll
    for (int jj = 0; jj < 6; ++jj) acc2[i][jj] = (f4v)0.f;
  float rsum[2][4];
#pragma unroll
  for (int i = 0; i < 2; ++i)
#pragma unroll
    for (int r = 0; r < 4; ++r) rsum[i][r] = 0.f;

  for (int j = 0; j < 8; ++j) {
    __syncthreads();                       // b1: prev-iter LDS reads done
    // ---- stage K_j (6 sub-tiles [64][32]) + V_j (2 sub-tiles [192][32]) ----
#pragma unroll
    for (int st = 0; st < 6; ++st)
      llds16(ksrc + (size_t)(j * 64) * HID + st * 32, lds + st * 2048 + w * 512);
#pragma unroll
    for (int st = 0; st < 2; ++st)
#pragma unroll
      for (int o = 0; o < 3; ++o)
        llds16(vsrc + (size_t)(o * 16) * SEQ + j * 64 + st * 32,
               lds + 12288 + st * 6144 + w * 1536 + o * 512);
    __syncthreads();                       // b2: vmcnt(0) drain + visibility
    // ---- QK^T: 24 MFMA/wave (64Q x 32K per wave) ----
    f4v sacc[2][2];
    sacc[0][0] = (f4v)0.f; sacc[0][1] = (f4v)0.f;
    sacc[1][0] = (f4v)0.f; sacc[1][1] = (f4v)0.f;
    __builtin_amdgcn_s_setprio(1);
#pragma unroll
    for (int ks = 0; ks < 6; ++ks) {
      h8v kf0 = *(const h8v*)&lds[ks * 2048 + (ch2 * 32 + ml) * 32 + fo2];
      h8v kf1 = *(const h8v*)&lds[ks * 2048 + (ch2 * 32 + 16 + ml) * 32 + fo2];
      sacc[0][0] = __builtin_amdgcn_mfma_f32_16x16x32_f16(qf[0][ks], kf0, sacc[0][0], 0, 0, 0);
      sacc[1][0] = __builtin_amdgcn_mfma_f32_16x16x32_f16(qf[1][ks], kf0, sacc[1][0], 0, 0, 0);
      sacc[0][1] = __builtin_amdgcn_mfma_f32_16x16x32_f16(qf[0][ks], kf1, sacc[0][1], 0, 0, 0);
      sacc[1][1] = __builtin_amdgcn_mfma_f32_16x16x32_f16(qf[1][ks], kf1, sacc[1][1], 0, 0, 0);
    }
    __builtin_amdgcn_s_setprio(0);
    // ---- transform + P write (max-free exp; 1 exp/elem via g-table) ----
#pragma unroll
    for (int i = 0; i < 2; ++i)
#pragma unroll
      for (int j2 = 0; j2 < 2; ++j2) {
        const int lcol = ch2 * 32 + j2 * 16 + ml;
        const int scolg = j * 64 + lcol;
#pragma unroll
        for (int r = 0; r < 4; ++r) {
          const int lrow = rh * 32 + i * 16 + quad * 4 + r;
          const float g = gtab[bm + lrow - scolg + 511];
          const float p = __expf(fmaf(sacc[i][j2][r], INV_SQRT_D, g));
          rsum[i][r] += p;
          lds[24576 + lrow * 72 + lcol] = f2h(p);
        }
      }
    __syncthreads();                       // b3: P_j visible
    // ---- PV: 24 MFMA/wave (64Q x 96 head-dims per wave) ----
    __builtin_amdgcn_s_setprio(1);
#pragma unroll
    for (int ks = 0; ks < 2; ++ks) {
      h8v pf[2], vf[6];
#pragma unroll
      for (int i = 0; i < 2; ++i)
        pf[i] = *(const h8v*)&lds[24576 + (rh * 32 + i * 16 + ml) * 72 + ks * 32 + quad * 8];
#pragma unroll
      for (int jj = 0; jj < 6; ++jj)
        vf[jj] = *(const h8v*)&lds[12288 + ks * 6144 + (ch2 * 96 + jj * 16 + ml) * 32 + fo2];
#pragma unroll
      for (int i = 0; i < 2; ++i)
#pragma unroll
        for (int jj = 0; jj < 6; ++jj)
          acc2[i][jj] = __builtin_amdgcn_mfma_f32_16x16x32_f16(pf[i], vf[jj], acc2[i][jj], 0, 0, 0);
    }
    __builtin_amdgcn_s_setprio(0);
  }

  // ---- final row-sum reduce ----
#pragma unroll
  for (int i = 0; i < 2; ++i)
#pragma unroll
    for (int r = 0; r < 4; ++r) {
      float t = rsum[i][r];
#pragma unroll
      for (int o = 1; o < 16; o <<= 1) t += __shfl_xor(t, o, 64);
      rsum[i][r] = t;
    }
  if (ml == 0) {
#pragma unroll
    for (int i = 0; i < 2; ++i)
#pragma unroll
      for (int r = 0; r < 4; ++r) red[w][i * 16 + quad * 4 + r] = rsum[i][r];
  }
  __syncthreads();

  // ---- ctx out (normalize here) ----
#pragma unroll
  for (int i = 0; i < 2; ++i)
#pragma unroll
    for (int r = 0; r < 4; ++r) {
      const int lr = i * 16 + quad * 4 + r;
      const float is = 1.0f / (red[rh * 2][lr] + red[rh * 2 + 1][lr]);
      const int m = bm + rh * 32 + lr;
#pragma unroll
      for (int jj = 0; jj < 6; ++jj) {
        const int gcol = hh * 192 + ch2 * 96 + jj * 16 + ml;
        ch[(size_t)(b * SEQ + m) * HID + gcol] = f2h(acc2[i][jj][r] * is);
      }
    }
}

// ---- projection GEMM + bias + residual -> h fp32 (XCD-swizzled, gll fp16) ----
__global__ __launch_bounds__(256, 4) void proj_mm(
    const u16* __restrict__ ch, const u16* __restrict__ WTh,
    const float* __restrict__ bo, const float* __restrict__ x, float* __restrict__ h)
{
  __shared__ u16 lds[16384];
  const int id = blockIdx.x;
  const int xcd = id & 7;
  const int s = id >> 3;            // 0..47
  const int bx = s % 6;
  const int yl = s / 6;             // 0..7
  const int bm = (yl * 8 + xcd) * 128;
  const int bn = bx * 128;
  const size_t wtoff = (size_t)3 * HID * HID + (size_t)bn * HID;
  f4v acc[4][4];
#pragma unroll
  for (int i = 0; i < 4; ++i)
#pragma unroll
    for (int j = 0; j < 4; ++j) acc[i][j] = (f4v)0.f;
  mm_core128<24>(ch + (size_t)bm * HID, HID, WTh + wtoff, HID, lds, acc);
  const int tid = threadIdx.x, w = tid >> 6, ln = tid & 63;
  const int ml = ln & 15, quad = ln >> 4;
  const int wr = (w >> 1) * 64, wc = (w & 1) * 64;
#pragma unroll
  for (int i = 0; i < 4; ++i)
#pragma unroll
    for (int j = 0; j < 4; ++j) {
      const int gcol = bn + wc + j * 16 + ml;
      const float bv_ = bo[gcol];
#pragma unroll
      for (int r = 0; r < 4; ++r) {
        const int grow = bm + wr + i * 16 + quad * 4 + r;
        const size_t idx = (size_t)grow * HID + gcol;
        h[idx] = acc[i][j][r] + bv_ + x[idx];
      }
    }
}

// ---- LayerNorm + 9-label classifier: ONE WAVE per row (R15).
//      shfl_xor-only reductions -> zero barriers, zero LDS. 4 rows/block. ----
__global__ __launch_bounds__(256) void ln_logits_kernel(
    const float* __restrict__ h, const float* __restrict__ g,
    const float* __restrict__ bta, const float* __restrict__ Ws,
    const float* __restrict__ bsv, float* __restrict__ span)
{
  const int row = blockIdx.x * 4 + (threadIdx.x >> 6);
  const int lane = threadIdx.x & 63;
  const float* hr = h + (size_t)row * HID;
  float4 v[3];
#pragma unroll
  for (int sgm = 0; sgm < 3; ++sgm) v[sgm] = ((const float4*)hr)[sgm * 64 + lane];
  float s = 0.f, sq = 0.f;
#pragma unroll
  for (int sgm = 0; sgm < 3; ++sgm) {
    s  += v[sgm].x + v[sgm].y + v[sgm].z + v[sgm].w;
    sq += v[sgm].x * v[sgm].x + v[sgm].y * v[sgm].y
        + v[sgm].z * v[sgm].z + v[sgm].w * v[sgm].w;
  }
#pragma unroll
  for (int o = 1; o < 64; o <<= 1) { s += __shfl_xor(s, o, 64); sq += __shfl_xor(sq, o, 64); }
  const float mu = s / 768.0f;
  const float rs = rsqrtf(sq / 768.0f - mu * mu + 1e-5f);
  float pl[9];
#pragma unroll
  for (int l = 0; l < 9; ++l) pl[l] = 0.f;
#pragma unroll
  for (int sgm = 0; sgm < 3; ++sgm) {
    const int c0 = sgm * 256 + lane * 4;
    const float4 gg = ((const float4*)g)[sgm * 64 + lane];
    const float4 bb = ((const float4*)bta)[sgm * 64 + lane];
    const float n0 = (v[sgm].x - mu) * rs * gg.x + bb.x;
    const float n1 = (v[sgm].y - mu) * rs * gg.y + bb.y;
    const float n2 = (v[sgm].z - mu) * rs * gg.z + bb.z;
    const float n3 = (v[sgm].w - mu) * rs * gg.w + bb.w;
    const float* w0 = Ws + (size_t)c0 * 9;
#pragma unroll
    for (int l = 0; l < 9; ++l)
      pl[l] += n0 * w0[l] + n1 * w0[9 + l] + n2 * w0[18 + l] + n3 * w0[27 + l];
  }
#pragma unroll
  for (int l = 0; l < 9; ++l)
#pragma unroll
    for (int o = 1; o < 64; o <<= 1) pl[l] += __shfl_xor(pl[l], o, 64);
  if (lane == 0) {
    float* sp = span + (size_t)row * 9;
#pragma unroll
    for (int l = 0; l < 9; ++l) sp[l] = pl[l] + bsv[l];
  }
}

// ---- entity-bias bump ----
__global__ __launch_bounds__(256) void bump_kernel(
    const float* __restrict__ span, const float* __restrict__ eb, float* __restrict__ out)
{
  const int idx = blockIdx.x * 256 + threadIdx.x;
  if (idx >= ROWS) return;
  const int j = idx & (SEQ - 1);
  const float* sl = span + (size_t)idx * 9;
  float v[9];
#pragma unroll
  for (int l = 0; l < 9; ++l) v[l] = sl[l];
  if (j >= 1) {
    const float* sp = sl - 9;
    float m = sp[0]; int am = 0;
#pragma unroll
    for (int l = 1; l < 9; ++l) { const float t = sp[l]; if (t > m) { m = t; am = l; } }
    if (am == 1) v[2] += 2.0f * eb[2];
  }
#pragma unroll
  for (int l = 0; l < 9; ++l) out[(size_t)idx * 9 + l] = v[l];
}

extern "C" void kernel_launch(void* const* d_in, const int* in_sizes, int n_in,
                              void* d_out, int out_size, void* d_ws, size_t ws_size,
                              hipStream_t stream)
{
  (void)in_sizes; (void)n_in; (void)out_size; (void)ws_size;
  const float* x   = (const float*)d_in[0];
  const float* Wq  = (const float*)d_in[1];
  const float* bq  = (const float*)d_in[2];
  const float* Wk  = (const float*)d_in[3];
  const float* bk  = (const float*)d_in[4];
  const float* Wv  = (const float*)d_in[5];
  const float* bv  = (const float*)d_in[6];
  const float* Wo  = (const float*)d_in[7];
  const float* bo  = (const float*)d_in[8];
  const float* lng = (const float*)d_in[9];
  const float* lnb = (const float*)d_in[10];
  const float* Ws  = (const float*)d_in[11];
  const float* bs  = (const float*)d_in[12];
  const float* eb  = (const float*)d_in[13];
  float* out = (float*)d_out;

  char* ws = (char*)d_ws;
  u16* xh  = (u16*)(ws + 0);                       // fp16 x (12.6MB)
  u16* WTh = (u16*)(ws + 25165824);                // fp16 WT (4 matrices)
  u16* qh  = (u16*)(ws + 34603008);
  u16* kh  = (u16*)(ws + 59768832);
  u16* vTh = (u16*)(ws + 84934656);                // fp16 vT (12.6MB)
  float* hb = (float*)(ws + 84934656);             // fp32 h (25MB, overwrites vT after attn)
  float* spanb = (float*)(ws + 152043520);
  u16* ctxh = qh;                                  // q dead after attn

  splitx<<<dim3(1572864 / 256), 256, 0, stream>>>(x, xh);
  wsplit<<<dim3(24, 24, 4), 256, 0, stream>>>(Wq, Wk, Wv, Wo, WTh);
  qkv_mm<<<dim3(1152), 256, 0, stream>>>(xh, WTh, bq, bk, bv, qh, kh, vTh);
  attn_fused<<<dim3(512), 256, 0, stream>>>(qh, kh, vTh, ctxh);
  proj_mm<<<dim3(384), 256, 0, stream>>>(ctxh, WTh, bo, x, hb);
  ln_logits_kernel<<<dim3(ROWS / 4), 256, 0, stream>>>(hb, lng, lnb, Ws, bs, spanb);
  bump_kernel<<<dim3(ROWS / 256), 256, 0, stream>>>(spanb, eb, out);
}